// Round 10
// baseline (3091.216 us; speedup 1.0000x reference)
//
#include <hip/hip_runtime.h>

#define D 128
#define CLS 3
#define LAY 3
#define NBKT 8

// ---------------- CSR build ----------------
__global__ void k_count(const int* __restrict__ col, int* __restrict__ cnt, int E) {
  int e = blockIdx.x * blockDim.x + threadIdx.x;
  if (e < E) atomicAdd(&cnt[col[e]], 1);
}

// exclusive scan of PADDED counts: pad(cnt) = (cnt+15)&~15  -> rptr2
__global__ __launch_bounds__(1024) void k_exscan(const int* __restrict__ cnt,
                                                 int* __restrict__ ptr, int n) {
  __shared__ int wsum[16];
  __shared__ int s_carry;
  const int tid = threadIdx.x;
  const int lane = tid & 63, wid = tid >> 6;
  if (tid == 0) s_carry = 0;
  __syncthreads();
  for (int base = 0; base < n; base += 1024) {
    int i = base + tid;
    int v = (i < n) ? ((cnt[i] + 15) & ~15) : 0;
    int s = v;
#pragma unroll
    for (int off = 1; off < 64; off <<= 1) {
      int t = __shfl_up(s, off, 64);
      if (lane >= off) s += t;
    }
    if (lane == 63) wsum[wid] = s;
    __syncthreads();
    if (wid == 0 && lane < 16) {
      int ws = wsum[lane];
#pragma unroll
      for (int off = 1; off < 16; off <<= 1) {
        int t = __shfl_up(ws, off, 16);
        if (lane >= off) ws += t;
      }
      wsum[lane] = ws;
    }
    __syncthreads();
    int carry = s_carry;
    int woff = wid ? wsum[wid - 1] : 0;
    if (i < n) ptr[i] = carry + woff + (s - v);
    __syncthreads();
    if (tid == 1023) s_carry = carry + wsum[15];
    __syncthreads();
  }
  if (tid == 0) ptr[n] = s_carry;
}

// dinv + fill CSR padding slots with sentinel N
__global__ void k_prep(const int* __restrict__ cnt, const int* __restrict__ rptr2,
                       float* __restrict__ dinv, unsigned short* __restrict__ srcs, int N) {
  int i = blockIdx.x * blockDim.x + threadIdx.x;
  if (i < N) {
    dinv[i] = rsqrtf((float)(cnt[i] + 1));
    int e = rptr2[i] + cnt[i], e1 = rptr2[i + 1];
    for (; e < e1; ++e) srcs[e] = (unsigned short)N;  // sentinel -> zero row
  }
}

// phase A: bin edges into 8 even col-range buckets (fixed-stride pairs layout)
__global__ __launch_bounds__(256) void k_bin(const int* __restrict__ row,
                                             const int* __restrict__ col,
                                             int* __restrict__ bfill,
                                             unsigned* __restrict__ pairs,
                                             int E, float bscale, int bshift) {
  __shared__ int lh[NBKT], gbase[NBKT], lcur[NBKT];
  const int tid = threadIdx.x;
  const int chunk = (E + gridDim.x - 1) / gridDim.x;
  const int s0 = blockIdx.x * chunk;
  const int s1 = min(s0 + chunk, E);
  if (tid < NBKT) lh[tid] = 0;
  __syncthreads();
  for (int e = s0 + tid; e < s1; e += 256) {
    int b = min(NBKT - 1, (int)((float)col[e] * bscale));
    atomicAdd(&lh[b], 1);
  }
  __syncthreads();
  if (tid < NBKT) {
    gbase[tid] = atomicAdd(&bfill[tid], lh[tid]);
    lcur[tid] = 0;
  }
  __syncthreads();
  for (int e = s0 + tid; e < s1; e += 256) {
    int c = col[e], r = row[e];
    int b = min(NBKT - 1, (int)((float)c * bscale));
    int off = atomicAdd(&lcur[b], 1);
    pairs[(b << bshift) + gbase[b] + off] = ((unsigned)r << 16) | (unsigned)c;
  }
}

// phase B: XCD-affine scatter into padded CSR (bucket b only on blocks with blockIdx&7==b)
__global__ __launch_bounds__(256) void k_fill2(const unsigned* __restrict__ pairs,
                                               const int* __restrict__ bfill,
                                               const int* __restrict__ rptr2,
                                               int* __restrict__ fillc,
                                               unsigned short* __restrict__ srcs,
                                               int bshift) {
  const int b = blockIdx.x & 7;
  const int bi = blockIdx.x >> 3;
  const int cap = bfill[b];
  const int stride = (gridDim.x >> 3) * blockDim.x;
  const unsigned* __restrict__ bp = pairs + ((size_t)b << bshift);
  for (int idx = bi * blockDim.x + threadIdx.x; idx < cap; idx += stride) {
    unsigned p = bp[idx];
    int c = (int)(p & 0xFFFFu);
    int pos = rptr2[c] + atomicAdd(&fillc[c], 1);
    srcs[pos] = (unsigned short)(p >> 16);
  }
}

// zero the 8 sentinel rows of each of the 3 slice tables
__global__ void k_zsent(float* __restrict__ Tall, int N) {
  int t = blockIdx.x * blockDim.x + threadIdx.x;   // 3*8*16 = 384
  if (t < CLS * 8 * 16) {
    int c = t / 128, rem = t % 128;
    int s = rem / 16, f = rem % 16;
    Tall[((size_t)c * 8 + s) * (size_t)(N + 1) * 16 + (size_t)N * 16 + f] = 0.f;
  }
}

// ---- T0 = x * dinv, slice-major [8][N+1][16] ----
__global__ __launch_bounds__(256) void k_scale(const float* __restrict__ x,
                                               const float* __restrict__ dinv,
                                               float* __restrict__ T, int N) {
  const int s = blockIdx.y;
  const int i = blockIdx.x * 64 + (threadIdx.x >> 2);
  const int f = threadIdx.x & 3;
  if (i < N) {
    float4 v = *(const float4*)&x[(size_t)i * 128 + s * 16 + f * 4];
    float d = dinv[i];
    v.x *= d; v.y *= d; v.z *= d; v.w *= d;
    *(float4*)&T[((size_t)s * (N + 1) + i) * 16 + f * 4] = v;
  }
}

// ---- XCD-sliced gather: Z[i] = dinv[i]*(T[i] + sum T[srcs])  (padded CSR, u16 srcs) ----
// sched_barrier(0) between load block and accumulate block forces 16 loads in flight.
__global__ __launch_bounds__(256, 4) void k_gather(const float* __restrict__ T,
                                                   const int* __restrict__ rptr2,
                                                   const unsigned short* __restrict__ srcs,
                                                   const float* __restrict__ dinv,
                                                   float* __restrict__ Z, int N) {
  const int s = blockIdx.x & 7;
  const int chunk = blockIdx.x >> 3;
  const int i = chunk * 64 + (threadIdx.x >> 2);
  const int f = threadIdx.x & 3;
  if (i >= N) return;
  const float4* __restrict__ Ts = (const float4*)(T + (size_t)s * (N + 1) * 16);
  const int e0 = rptr2[i], e1 = rptr2[i + 1];
  float4 a0 = Ts[(size_t)i * 4 + f];  // self term
  float4 a1 = make_float4(0.f, 0.f, 0.f, 0.f);
  float4 a2 = make_float4(0.f, 0.f, 0.f, 0.f);
  float4 a3 = make_float4(0.f, 0.f, 0.f, 0.f);
  ushort4 q = make_ushort4(0, 0, 0, 0);
  if (e0 < e1) q = *(const ushort4*)(srcs + e0 + (f << 2));
  for (int eb = e0; eb < e1; eb += 16) {
    ushort4 qn = q;
    if (eb + 16 < e1) qn = *(const ushort4*)(srcs + eb + 16 + (f << 2));
    const int qx = q.x, qy = q.y, qz = q.z, qw = q.w;
    float4 v[16];
#pragma unroll
    for (int k = 0; k < 16; ++k) {
      const int comp = k & 3;
      const int val = comp == 0 ? qx : comp == 1 ? qy : comp == 2 ? qz : qw;
      const int j = __shfl(val, k >> 2, 4);
      v[k] = Ts[(size_t)j * 4 + f];
    }
    __builtin_amdgcn_sched_barrier(0);  // keep all 16 gathers issued before consumption
#pragma unroll
    for (int k = 0; k < 16; k += 4) {
      a0.x += v[k].x;     a0.y += v[k].y;     a0.z += v[k].z;     a0.w += v[k].w;
      a1.x += v[k + 1].x; a1.y += v[k + 1].y; a1.z += v[k + 1].z; a1.w += v[k + 1].w;
      a2.x += v[k + 2].x; a2.y += v[k + 2].y; a2.z += v[k + 2].z; a2.w += v[k + 2].w;
      a3.x += v[k + 3].x; a3.y += v[k + 3].y; a3.z += v[k + 3].z; a3.w += v[k + 3].w;
    }
    q = qn;
  }
  const float d = dinv[i];
  float4 r;
  r.x = (a0.x + a1.x + a2.x + a3.x) * d;
  r.y = (a0.y + a1.y + a2.y + a3.y) * d;
  r.z = (a0.z + a1.z + a2.z + a3.z) * d;
  r.w = (a0.w + a1.w + a2.w + a3.w) * d;
  *(float4*)&Z[(size_t)i * 128 + s * 16 + f * 4] = r;
}

// ---- batched 3-class GEMM + bias + L2-norm + ReLU (+dinv, slice-major) ----
// 128x128 tile, BK=16, double-buffered LDS (one barrier/K-step, loads overlap compute),
// 8x8 micro-tile rows split 4+4 at distance 64 (conflict-free A reads), red aliased.
template <int MODE>
__global__ __launch_bounds__(256, 4) void k_gemm3(const float* __restrict__ Abase, long astride,
                                                  const float* __restrict__ Wl,
                                                  const float* __restrict__ bl,
                                                  const float* __restrict__ dinv,
                                                  float* __restrict__ Obase, long ostride,
                                                  int N) {
  __shared__ __align__(16) char smem_raw[4 * 16 * 128 * 4];  // 32 KB: As0|Ws0|As1|Ws1
  float* __restrict__ As0 = (float*)smem_raw;
  float* __restrict__ Ws0 = (float*)(smem_raw + 8192);
  float* __restrict__ As1 = (float*)(smem_raw + 16384);
  float* __restrict__ Ws1 = (float*)(smem_raw + 24576);
  typedef float redrow[17];
  redrow* red = (redrow*)smem_raw;  // [128][17] epilogue-only, aliases As0/Ws0

  const int c = blockIdx.y;
  const float* __restrict__ A = Abase + (size_t)c * astride;
  const float* __restrict__ W = Wl + (size_t)c * (LAY * D * D);
  const float* __restrict__ bias = bl + (size_t)c * (LAY * D);
  float* __restrict__ Out = Obase + (size_t)c * ostride;

  const int tid = threadIdx.x;
  const int tr = tid & 15;
  const int tc = tid >> 4;
  const int m0 = blockIdx.x * 128;
  float acc[8][8];
#pragma unroll
  for (int i = 0; i < 8; ++i)
#pragma unroll
    for (int j = 0; j < 8; ++j) acc[i][j] = 0.f;

  const int lr = tid >> 1;       // 0..127 A row in tile
  const int lq = tid & 1;        // k half
  const int kr0 = tid >> 5;      // 0..7 W stage row
  const int cq = tid & 31;       // W stage col quad
  const int gr_l = m0 + lr;
  const bool arow = gr_l < N;

  float4 va0, va1, vw0, vw1;
  auto loadT = [&](int kc) {
    va0 = make_float4(0.f, 0.f, 0.f, 0.f);
    va1 = va0;
    if (arow) {
      va0 = *(const float4*)&A[(size_t)gr_l * 128 + kc + lq * 8];
      va1 = *(const float4*)&A[(size_t)gr_l * 128 + kc + lq * 8 + 4];
    }
    vw0 = *(const float4*)&W[(size_t)(kc + kr0) * 128 + cq * 4];
    vw1 = *(const float4*)&W[(size_t)(kc + 8 + kr0) * 128 + cq * 4];
  };
  auto stage = [&](float* __restrict__ Asf, float* __restrict__ Wsf) {
    Asf[(lq * 8 + 0) * 128 + lr] = va0.x;
    Asf[(lq * 8 + 1) * 128 + lr] = va0.y;
    Asf[(lq * 8 + 2) * 128 + lr] = va0.z;
    Asf[(lq * 8 + 3) * 128 + lr] = va0.w;
    Asf[(lq * 8 + 4) * 128 + lr] = va1.x;
    Asf[(lq * 8 + 5) * 128 + lr] = va1.y;
    Asf[(lq * 8 + 6) * 128 + lr] = va1.z;
    Asf[(lq * 8 + 7) * 128 + lr] = va1.w;
    *(float4*)&Wsf[kr0 * 128 + cq * 4] = vw0;
    *(float4*)&Wsf[(8 + kr0) * 128 + cq * 4] = vw1;
  };
  auto compute = [&](const float* __restrict__ Asf, const float* __restrict__ Wsf) {
#pragma unroll
    for (int kk = 0; kk < 16; ++kk) {
      float4 a4 = *(const float4*)&Asf[kk * 128 + tr * 4];
      float4 a4b = *(const float4*)&Asf[kk * 128 + 64 + tr * 4];
      float4 b4 = *(const float4*)&Wsf[kk * 128 + tc * 8];
      float4 b4b = *(const float4*)&Wsf[kk * 128 + tc * 8 + 4];
      float a[8] = {a4.x, a4.y, a4.z, a4.w, a4b.x, a4b.y, a4b.z, a4b.w};
      float b[8] = {b4.x, b4.y, b4.z, b4.w, b4b.x, b4b.y, b4b.z, b4b.w};
#pragma unroll
      for (int i = 0; i < 8; ++i)
#pragma unroll
        for (int j = 0; j < 8; ++j) acc[i][j] = fmaf(a[i], b[j], acc[i][j]);
    }
  };

  loadT(0);
  stage(As0, Ws0);
  __syncthreads();
#pragma unroll 1
  for (int kc = 0; kc < 128; kc += 32) {
    loadT(kc + 16);          // issue next-tile loads, drain under compute
    compute(As0, Ws0);
    stage(As1, Ws1);
    __syncthreads();
    if (kc + 32 < 128) loadT(kc + 32);
    compute(As1, Ws1);
    if (kc + 32 < 128) {
      stage(As0, Ws0);
      __syncthreads();
    }
  }
  __syncthreads();  // all compute done before red aliases As0/Ws0

  // epilogue: bias, row L2-norm, relu, (dinv), store. rows: tr*4+i and 64+tr*4+(i-4).
  const int c0 = tc * 8;
  float bj[8];
#pragma unroll
  for (int j = 0; j < 8; ++j) bj[j] = bias[c0 + j];
#pragma unroll
  for (int i = 0; i < 8; ++i) {
    const int r = (i < 4) ? (tr * 4 + i) : (64 + tr * 4 + i - 4);
    float rs = 0.f;
#pragma unroll
    for (int j = 0; j < 8; ++j) {
      acc[i][j] += bj[j];
      rs = fmaf(acc[i][j], acc[i][j], rs);
    }
    red[r][tc] = rs;
  }
  __syncthreads();
#pragma unroll
  for (int i = 0; i < 8; ++i) {
    const int r = (i < 4) ? (tr * 4 + i) : (64 + tr * 4 + i - 4);
    const int gr = m0 + r;
    if (gr >= N) continue;
    float rsum = 0.f;
#pragma unroll
    for (int q = 0; q < 16; ++q) rsum += red[r][q];
    float sc = 1.0f / fmaxf(sqrtf(rsum), 1e-12f);
    if (MODE == 0) sc *= dinv[gr];
    float4 o0, o1;
    o0.x = fmaxf(acc[i][0] * sc, 0.f);
    o0.y = fmaxf(acc[i][1] * sc, 0.f);
    o0.z = fmaxf(acc[i][2] * sc, 0.f);
    o0.w = fmaxf(acc[i][3] * sc, 0.f);
    o1.x = fmaxf(acc[i][4] * sc, 0.f);
    o1.y = fmaxf(acc[i][5] * sc, 0.f);
    o1.z = fmaxf(acc[i][6] * sc, 0.f);
    o1.w = fmaxf(acc[i][7] * sc, 0.f);
    if (MODE == 0) {
      size_t base = ((size_t)(tc >> 1) * (N + 1) + gr) * 16 + (tc & 1) * 8;
      *(float4*)&Out[base] = o0;
      *(float4*)&Out[base + 4] = o1;
    } else {
      *(float4*)&Out[(size_t)gr * 128 + c0] = o0;
      *(float4*)&Out[(size_t)gr * 128 + c0 + 4] = o1;
    }
  }
}

// ------------- batched head: pool + lin1 + ReLU + lin2 (blockIdx.y = class) -------------
__device__ __forceinline__ int lowerb(const int* __restrict__ a, int n, int v) {
  int lo = 0, hi = n;
  while (lo < hi) {
    int m = (lo + hi) >> 1;
    if (a[m] < v) lo = m + 1; else hi = m;
  }
  return lo;
}

__global__ __launch_bounds__(128) void k_head(const float* __restrict__ Hall, long hstride,
                                              const int* __restrict__ batch, int N,
                                              const float* __restrict__ l1w,
                                              const float* __restrict__ l1b,
                                              const float* __restrict__ l2w,
                                              const float* __restrict__ l2b,
                                              float* __restrict__ out, int G) {
  const int g = blockIdx.x;
  const int c = blockIdx.y;
  const int t = threadIdx.x;
  const float* __restrict__ h = Hall + (size_t)c * hstride;
  const float* __restrict__ w1 = l1w + (size_t)c * D * D;
  const float* __restrict__ w2 = l2w + (size_t)c * D;
  int lo = lowerb(batch, N, g);
  int hi = lowerb(batch, N, g + 1);
  float p = 0.f;
  for (int i = lo; i < hi; ++i) p += h[(size_t)i * 128 + t];
  __shared__ float pl[128];
  pl[t] = p;
  __syncthreads();
  float z = l1b[(size_t)c * D + t];
#pragma unroll 8
  for (int k = 0; k < 128; ++k) z = fmaf(pl[k], w1[k * 128 + t], z);
  z = fmaxf(z, 0.f);
  float o = z * w2[t];
#pragma unroll
  for (int off = 32; off > 0; off >>= 1) o += __shfl_xor(o, off, 64);
  __shared__ float s2[2];
  if ((t & 63) == 0) s2[t >> 6] = o;
  __syncthreads();
  if (t == 0) out[(size_t)g * CLS + c] = s2[0] + s2[1] + l2b[c];
}

extern "C" void kernel_launch(void* const* d_in, const int* in_sizes, int n_in,
                              void* d_out, int out_size, void* d_ws, size_t ws_size,
                              hipStream_t stream) {
  const float* x = (const float*)d_in[0];
  const int* eidx = (const int*)d_in[1];
  const int* batch = (const int*)d_in[2];
  const float* conv_w = (const float*)d_in[3];
  const float* conv_b = (const float*)d_in[4];
  const float* lin1_w = (const float*)d_in[5];
  const float* lin1_b = (const float*)d_in[6];
  const float* lin2_w = (const float*)d_in[7];
  const float* lin2_b = (const float*)d_in[8];
  float* out = (float*)d_out;

  const int N = in_sizes[0] / D;
  const int E = in_sizes[1] / 2;
  const int G = out_size / CLS;
  const int* row = eidx;
  const int* col = eidx + E;

  int bshift = 10;
  while ((1 << bshift) < E / NBKT + 32768) ++bshift;
  const long TS = (long)(N + 1) * 128;  // per-class slice-table stride (floats)
  const long ZS = (long)N * 128;        // per-class row-major stride (floats)

  char* ws = (char*)d_ws;
  size_t off = 0;
  auto alloc = [&](size_t bytes) -> void* {
    void* p = ws + off;
    off += (bytes + 255) & ~(size_t)255;
    return p;
  };
  float* Zall = (float*)alloc((size_t)CLS * ZS * 4);
  float* Tall = (float*)alloc((size_t)CLS * TS * 4);
  unsigned short* srcs = (unsigned short*)alloc(((size_t)E + 16 * (size_t)N + 64) * 2);
  int* cnt    = (int*)alloc(((size_t)N * 2 + NBKT) * 4);
  int* fillc  = cnt + N;
  int* bfill  = cnt + 2 * N;
  int* rptr2  = (int*)alloc((size_t)(N + 1) * 4);
  float* dinv = (float*)alloc((size_t)N * 4);
  unsigned* pairs = (unsigned*)Tall;  // alias: dead before k_zsent/k_scale
  (void)ws_size; (void)n_in;

  hipMemsetAsync(cnt, 0, ((size_t)N * 2 + NBKT) * 4, stream);
  const int eb = (E + 255) / 256;
  const int nb = (N + 255) / 256;
  k_count<<<eb, 256, 0, stream>>>(col, cnt, E);
  k_exscan<<<1, 1024, 0, stream>>>(cnt, rptr2, N);
  k_prep<<<nb, 256, 0, stream>>>(cnt, rptr2, dinv, srcs, N);
  k_bin<<<1024, 256, 0, stream>>>(row, col, bfill, pairs, E, (float)NBKT / (float)N, bshift);
  k_fill2<<<1024, 256, 0, stream>>>(pairs, bfill, rptr2, fillc, srcs, bshift);
  k_zsent<<<2, 256, 0, stream>>>(Tall, N);

  const int NB64 = (N + 63) / 64;
  const int gb = (N + 127) / 128;
  float* Z0 = Zall;

  // shared layer 0
  k_scale<<<dim3(NB64, 8), 256, 0, stream>>>(x, dinv, Tall, N);
  k_gather<<<NB64 * 8, 256, 0, stream>>>(Tall, rptr2, srcs, dinv, Z0, N);

  // layer 1 (A shared across classes)
  k_gemm3<0><<<dim3(gb, CLS), 256, 0, stream>>>(Z0, 0L, conv_w + 0 * D * D,
                                                conv_b + 0 * D, dinv, Tall, TS, N);
  for (int c = 0; c < CLS; ++c)
    k_gather<<<NB64 * 8, 256, 0, stream>>>(Tall + c * TS, rptr2, srcs, dinv, Zall + c * ZS, N);

  // layer 2
  k_gemm3<0><<<dim3(gb, CLS), 256, 0, stream>>>(Zall, ZS, conv_w + 1 * D * D,
                                                conv_b + 1 * D, dinv, Tall, TS, N);
  for (int c = 0; c < CLS; ++c)
    k_gather<<<NB64 * 8, 256, 0, stream>>>(Tall + c * TS, rptr2, srcs, dinv, Zall + c * ZS, N);

  // layer 3 -> H (row-major, stored in the table slots)
  k_gemm3<1><<<dim3(gb, CLS), 256, 0, stream>>>(Zall, ZS, conv_w + 2 * D * D,
                                                conv_b + 2 * D, dinv, Tall, TS, N);

  // heads
  k_head<<<dim3(G, CLS), 128, 0, stream>>>(Tall, TS, batch, N,
                                           lin1_w, lin1_b, lin2_w, lin2_b, out, G);
}

// Round 11
// 921.757 us; speedup vs baseline: 3.3536x; 3.3536x over previous
//
#include <hip/hip_runtime.h>

#define D 128
#define CLS 3
#define LAY 3
#define NBKT 8

// ---------------- CSR build ----------------
__global__ void k_count(const int* __restrict__ col, int* __restrict__ cnt, int E) {
  int e = blockIdx.x * blockDim.x + threadIdx.x;
  if (e < E) atomicAdd(&cnt[col[e]], 1);
}

// exclusive scan of PADDED counts: pad(cnt) = (cnt+15)&~15  -> rptr2
__global__ __launch_bounds__(1024) void k_exscan(const int* __restrict__ cnt,
                                                 int* __restrict__ ptr, int n) {
  __shared__ int wsum[16];
  __shared__ int s_carry;
  const int tid = threadIdx.x;
  const int lane = tid & 63, wid = tid >> 6;
  if (tid == 0) s_carry = 0;
  __syncthreads();
  for (int base = 0; base < n; base += 1024) {
    int i = base + tid;
    int v = (i < n) ? ((cnt[i] + 15) & ~15) : 0;
    int s = v;
#pragma unroll
    for (int off = 1; off < 64; off <<= 1) {
      int t = __shfl_up(s, off, 64);
      if (lane >= off) s += t;
    }
    if (lane == 63) wsum[wid] = s;
    __syncthreads();
    if (wid == 0 && lane < 16) {
      int ws = wsum[lane];
#pragma unroll
      for (int off = 1; off < 16; off <<= 1) {
        int t = __shfl_up(ws, off, 16);
        if (lane >= off) ws += t;
      }
      wsum[lane] = ws;
    }
    __syncthreads();
    int carry = s_carry;
    int woff = wid ? wsum[wid - 1] : 0;
    if (i < n) ptr[i] = carry + woff + (s - v);
    __syncthreads();
    if (tid == 1023) s_carry = carry + wsum[15];
    __syncthreads();
  }
  if (tid == 0) ptr[n] = s_carry;
}

// dinv + fill CSR padding slots with sentinel N
__global__ void k_prep(const int* __restrict__ cnt, const int* __restrict__ rptr2,
                       float* __restrict__ dinv, unsigned short* __restrict__ srcs, int N) {
  int i = blockIdx.x * blockDim.x + threadIdx.x;
  if (i < N) {
    dinv[i] = rsqrtf((float)(cnt[i] + 1));
    int e = rptr2[i] + cnt[i], e1 = rptr2[i + 1];
    for (; e < e1; ++e) srcs[e] = (unsigned short)N;  // sentinel -> zero row
  }
}

// phase A: bin edges into 8 even col-range buckets (fixed-stride pairs layout)
__global__ __launch_bounds__(256) void k_bin(const int* __restrict__ row,
                                             const int* __restrict__ col,
                                             int* __restrict__ bfill,
                                             unsigned* __restrict__ pairs,
                                             int E, float bscale, int bshift) {
  __shared__ int lh[NBKT], gbase[NBKT], lcur[NBKT];
  const int tid = threadIdx.x;
  const int chunk = (E + gridDim.x - 1) / gridDim.x;
  const int s0 = blockIdx.x * chunk;
  const int s1 = min(s0 + chunk, E);
  if (tid < NBKT) lh[tid] = 0;
  __syncthreads();
  for (int e = s0 + tid; e < s1; e += 256) {
    int b = min(NBKT - 1, (int)((float)col[e] * bscale));
    atomicAdd(&lh[b], 1);
  }
  __syncthreads();
  if (tid < NBKT) {
    gbase[tid] = atomicAdd(&bfill[tid], lh[tid]);
    lcur[tid] = 0;
  }
  __syncthreads();
  for (int e = s0 + tid; e < s1; e += 256) {
    int c = col[e], r = row[e];
    int b = min(NBKT - 1, (int)((float)c * bscale));
    int off = atomicAdd(&lcur[b], 1);
    pairs[(b << bshift) + gbase[b] + off] = ((unsigned)r << 16) | (unsigned)c;
  }
}

// phase B: XCD-affine scatter into padded CSR (bucket b only on blocks with blockIdx&7==b)
__global__ __launch_bounds__(256) void k_fill2(const unsigned* __restrict__ pairs,
                                               const int* __restrict__ bfill,
                                               const int* __restrict__ rptr2,
                                               int* __restrict__ fillc,
                                               unsigned short* __restrict__ srcs,
                                               int bshift) {
  const int b = blockIdx.x & 7;
  const int bi = blockIdx.x >> 3;
  const int cap = bfill[b];
  const int stride = (gridDim.x >> 3) * blockDim.x;
  const unsigned* __restrict__ bp = pairs + ((size_t)b << bshift);
  for (int idx = bi * blockDim.x + threadIdx.x; idx < cap; idx += stride) {
    unsigned p = bp[idx];
    int c = (int)(p & 0xFFFFu);
    int pos = rptr2[c] + atomicAdd(&fillc[c], 1);
    srcs[pos] = (unsigned short)(p >> 16);
  }
}

// zero the 8 sentinel rows of each of the 3 slice tables
__global__ void k_zsent(float* __restrict__ Tall, int N) {
  int t = blockIdx.x * blockDim.x + threadIdx.x;   // 3*8*16 = 384
  if (t < CLS * 8 * 16) {
    int c = t / 128, rem = t % 128;
    int s = rem / 16, f = rem % 16;
    Tall[((size_t)c * 8 + s) * (size_t)(N + 1) * 16 + (size_t)N * 16 + f] = 0.f;
  }
}

// ---- T0 = x * dinv, slice-major [8][N+1][16] ----
__global__ __launch_bounds__(256) void k_scale(const float* __restrict__ x,
                                               const float* __restrict__ dinv,
                                               float* __restrict__ T, int N) {
  const int s = blockIdx.y;
  const int i = blockIdx.x * 64 + (threadIdx.x >> 2);
  const int f = threadIdx.x & 3;
  if (i < N) {
    float4 v = *(const float4*)&x[(size_t)i * 128 + s * 16 + f * 4];
    float d = dinv[i];
    v.x *= d; v.y *= d; v.z *= d; v.w *= d;
    *(float4*)&T[((size_t)s * (N + 1) + i) * 16 + f * 4] = v;
  }
}

// ---- XCD-sliced gather, fused over classes (blockIdx.y = class) ----
// Z[i] = dinv[i]*(T[i] + sum T[srcs]); padded CSR, u16 srcs.
// sched_barrier(0) between load block and accumulate block keeps 16 gathers in flight.
__global__ __launch_bounds__(256, 4) void k_gather(const float* __restrict__ Tbase, long tstride,
                                                   const int* __restrict__ rptr2,
                                                   const unsigned short* __restrict__ srcs,
                                                   const float* __restrict__ dinv,
                                                   float* __restrict__ Zbase, long zstride,
                                                   int N) {
  const int s = blockIdx.x & 7;
  const int chunk = blockIdx.x >> 3;
  const int i = chunk * 64 + (threadIdx.x >> 2);
  const int f = threadIdx.x & 3;
  if (i >= N) return;
  const float* __restrict__ T = Tbase + (size_t)blockIdx.y * tstride;
  float* __restrict__ Z = Zbase + (size_t)blockIdx.y * zstride;
  const float4* __restrict__ Ts = (const float4*)(T + (size_t)s * (N + 1) * 16);
  const int e0 = rptr2[i], e1 = rptr2[i + 1];
  float4 a0 = Ts[(size_t)i * 4 + f];  // self term
  float4 a1 = make_float4(0.f, 0.f, 0.f, 0.f);
  float4 a2 = make_float4(0.f, 0.f, 0.f, 0.f);
  float4 a3 = make_float4(0.f, 0.f, 0.f, 0.f);
  ushort4 q = make_ushort4(0, 0, 0, 0);
  if (e0 < e1) q = *(const ushort4*)(srcs + e0 + (f << 2));
  for (int eb = e0; eb < e1; eb += 16) {
    ushort4 qn = q;
    if (eb + 16 < e1) qn = *(const ushort4*)(srcs + eb + 16 + (f << 2));
    const int qx = q.x, qy = q.y, qz = q.z, qw = q.w;
    float4 v[16];
#pragma unroll
    for (int k = 0; k < 16; ++k) {
      const int comp = k & 3;
      const int val = comp == 0 ? qx : comp == 1 ? qy : comp == 2 ? qz : qw;
      const int j = __shfl(val, k >> 2, 4);
      v[k] = Ts[(size_t)j * 4 + f];
    }
    __builtin_amdgcn_sched_barrier(0);  // all 16 gathers issued before consumption
#pragma unroll
    for (int k = 0; k < 16; k += 4) {
      a0.x += v[k].x;     a0.y += v[k].y;     a0.z += v[k].z;     a0.w += v[k].w;
      a1.x += v[k + 1].x; a1.y += v[k + 1].y; a1.z += v[k + 1].z; a1.w += v[k + 1].w;
      a2.x += v[k + 2].x; a2.y += v[k + 2].y; a2.z += v[k + 2].z; a2.w += v[k + 2].w;
      a3.x += v[k + 3].x; a3.y += v[k + 3].y; a3.z += v[k + 3].z; a3.w += v[k + 3].w;
    }
    q = qn;
  }
  const float d = dinv[i];
  float4 r;
  r.x = (a0.x + a1.x + a2.x + a3.x) * d;
  r.y = (a0.y + a1.y + a2.y + a3.y) * d;
  r.z = (a0.z + a1.z + a2.z + a3.z) * d;
  r.w = (a0.w + a1.w + a2.w + a3.w) * d;
  *(float4*)&Z[(size_t)i * 128 + s * 16 + f * 4] = r;
}

// ---- batched 3-class GEMM + bias + L2-norm + ReLU (+dinv, slice-major) ----
// Round-9 version (proven 79us): 128x128 tile, BK=16, conflict-free A reads
// (rows split 4+4 at distance 64), red[] aliased over As/Ws (16 KB LDS).
template <int MODE>
__global__ __launch_bounds__(256, 4) void k_gemm3(const float* __restrict__ Abase, long astride,
                                                  const float* __restrict__ Wl,
                                                  const float* __restrict__ bl,
                                                  const float* __restrict__ dinv,
                                                  float* __restrict__ Obase, long ostride,
                                                  int N) {
  __shared__ __align__(16) char smem_raw[16 * 128 * 4 * 2];  // 16 KB
  float* __restrict__ Asf = (float*)smem_raw;                // [16][128]
  float* __restrict__ Wsf = (float*)(smem_raw + 8192);       // [16][128]
  typedef float redrow[17];
  redrow* red = (redrow*)smem_raw;                           // [128][17], epilogue only

  const int c = blockIdx.y;
  const float* __restrict__ A = Abase + (size_t)c * astride;
  const float* __restrict__ W = Wl + (size_t)c * (LAY * D * D);
  const float* __restrict__ bias = bl + (size_t)c * (LAY * D);
  float* __restrict__ Out = Obase + (size_t)c * ostride;

  const int tid = threadIdx.x;
  const int tr = tid & 15;
  const int tc = tid >> 4;
  const int m0 = blockIdx.x * 128;
  float acc[8][8];
#pragma unroll
  for (int i = 0; i < 8; ++i)
#pragma unroll
    for (int j = 0; j < 8; ++j) acc[i][j] = 0.f;

  const int lr = tid >> 1;       // 0..127 A row in tile
  const int lq = tid & 1;        // k half
  const int gr_l = m0 + lr;

  for (int kc = 0; kc < 128; kc += 16) {
    float4 va0 = make_float4(0.f, 0.f, 0.f, 0.f), va1 = va0;
    if (gr_l < N) {
      va0 = *(const float4*)&A[(size_t)gr_l * 128 + kc + lq * 8];
      va1 = *(const float4*)&A[(size_t)gr_l * 128 + kc + lq * 8 + 4];
    }
    Asf[(lq * 8 + 0) * 128 + lr] = va0.x;
    Asf[(lq * 8 + 1) * 128 + lr] = va0.y;
    Asf[(lq * 8 + 2) * 128 + lr] = va0.z;
    Asf[(lq * 8 + 3) * 128 + lr] = va0.w;
    Asf[(lq * 8 + 4) * 128 + lr] = va1.x;
    Asf[(lq * 8 + 5) * 128 + lr] = va1.y;
    Asf[(lq * 8 + 6) * 128 + lr] = va1.z;
    Asf[(lq * 8 + 7) * 128 + lr] = va1.w;
#pragma unroll
    for (int it = 0; it < 2; ++it) {
      const int lin = tid + it * 256;
      const int kr = lin >> 5;
      const int cq = lin & 31;
      *(float4*)&Wsf[kr * 128 + cq * 4] = *(const float4*)&W[(size_t)(kc + kr) * 128 + cq * 4];
    }
    __syncthreads();
#pragma unroll
    for (int kk = 0; kk < 16; ++kk) {
      float4 a4 = *(const float4*)&Asf[kk * 128 + tr * 4];
      float4 a4b = *(const float4*)&Asf[kk * 128 + 64 + tr * 4];
      float4 b4 = *(const float4*)&Wsf[kk * 128 + tc * 8];
      float4 b4b = *(const float4*)&Wsf[kk * 128 + tc * 8 + 4];
      float a[8] = {a4.x, a4.y, a4.z, a4.w, a4b.x, a4b.y, a4b.z, a4b.w};
      float b[8] = {b4.x, b4.y, b4.z, b4.w, b4b.x, b4b.y, b4b.z, b4b.w};
#pragma unroll
      for (int i = 0; i < 8; ++i)
#pragma unroll
        for (int j = 0; j < 8; ++j) acc[i][j] = fmaf(a[i], b[j], acc[i][j]);
    }
    __syncthreads();
  }

  // epilogue: bias, row L2-norm, relu, (dinv), store. rows: tr*4+i and 64+tr*4+(i-4).
  const int c0 = tc * 8;
  float bj[8];
#pragma unroll
  for (int j = 0; j < 8; ++j) bj[j] = bias[c0 + j];
#pragma unroll
  for (int i = 0; i < 8; ++i) {
    const int r = (i < 4) ? (tr * 4 + i) : (64 + tr * 4 + i - 4);
    float rs = 0.f;
#pragma unroll
    for (int j = 0; j < 8; ++j) {
      acc[i][j] += bj[j];
      rs = fmaf(acc[i][j], acc[i][j], rs);
    }
    red[r][tc] = rs;
  }
  __syncthreads();
#pragma unroll
  for (int i = 0; i < 8; ++i) {
    const int r = (i < 4) ? (tr * 4 + i) : (64 + tr * 4 + i - 4);
    const int gr = m0 + r;
    if (gr >= N) continue;
    float rsum = 0.f;
#pragma unroll
    for (int q = 0; q < 16; ++q) rsum += red[r][q];
    float sc = 1.0f / fmaxf(sqrtf(rsum), 1e-12f);
    if (MODE == 0) sc *= dinv[gr];
    float4 o0, o1;
    o0.x = fmaxf(acc[i][0] * sc, 0.f);
    o0.y = fmaxf(acc[i][1] * sc, 0.f);
    o0.z = fmaxf(acc[i][2] * sc, 0.f);
    o0.w = fmaxf(acc[i][3] * sc, 0.f);
    o1.x = fmaxf(acc[i][4] * sc, 0.f);
    o1.y = fmaxf(acc[i][5] * sc, 0.f);
    o1.z = fmaxf(acc[i][6] * sc, 0.f);
    o1.w = fmaxf(acc[i][7] * sc, 0.f);
    if (MODE == 0) {
      size_t base = ((size_t)(tc >> 1) * (N + 1) + gr) * 16 + (tc & 1) * 8;
      *(float4*)&Out[base] = o0;
      *(float4*)&Out[base + 4] = o1;
    } else {
      *(float4*)&Out[(size_t)gr * 128 + c0] = o0;
      *(float4*)&Out[(size_t)gr * 128 + c0 + 4] = o1;
    }
  }
}

// ------------- batched head: pool + lin1 + ReLU + lin2 (blockIdx.y = class) -------------
__device__ __forceinline__ int lowerb(const int* __restrict__ a, int n, int v) {
  int lo = 0, hi = n;
  while (lo < hi) {
    int m = (lo + hi) >> 1;
    if (a[m] < v) lo = m + 1; else hi = m;
  }
  return lo;
}

__global__ __launch_bounds__(128) void k_head(const float* __restrict__ Hall, long hstride,
                                              const int* __restrict__ batch, int N,
                                              const float* __restrict__ l1w,
                                              const float* __restrict__ l1b,
                                              const float* __restrict__ l2w,
                                              const float* __restrict__ l2b,
                                              float* __restrict__ out, int G) {
  const int g = blockIdx.x;
  const int c = blockIdx.y;
  const int t = threadIdx.x;
  const float* __restrict__ h = Hall + (size_t)c * hstride;
  const float* __restrict__ w1 = l1w + (size_t)c * D * D;
  const float* __restrict__ w2 = l2w + (size_t)c * D;
  int lo = lowerb(batch, N, g);
  int hi = lowerb(batch, N, g + 1);
  float p = 0.f;
  for (int i = lo; i < hi; ++i) p += h[(size_t)i * 128 + t];
  __shared__ float pl[128];
  pl[t] = p;
  __syncthreads();
  float z = l1b[(size_t)c * D + t];
#pragma unroll 8
  for (int k = 0; k < 128; ++k) z = fmaf(pl[k], w1[k * 128 + t], z);
  z = fmaxf(z, 0.f);
  float o = z * w2[t];
#pragma unroll
  for (int off = 32; off > 0; off >>= 1) o += __shfl_xor(o, off, 64);
  __shared__ float s2[2];
  if ((t & 63) == 0) s2[t >> 6] = o;
  __syncthreads();
  if (t == 0) out[(size_t)g * CLS + c] = s2[0] + s2[1] + l2b[c];
}

extern "C" void kernel_launch(void* const* d_in, const int* in_sizes, int n_in,
                              void* d_out, int out_size, void* d_ws, size_t ws_size,
                              hipStream_t stream) {
  const float* x = (const float*)d_in[0];
  const int* eidx = (const int*)d_in[1];
  const int* batch = (const int*)d_in[2];
  const float* conv_w = (const float*)d_in[3];
  const float* conv_b = (const float*)d_in[4];
  const float* lin1_w = (const float*)d_in[5];
  const float* lin1_b = (const float*)d_in[6];
  const float* lin2_w = (const float*)d_in[7];
  const float* lin2_b = (const float*)d_in[8];
  float* out = (float*)d_out;

  const int N = in_sizes[0] / D;
  const int E = in_sizes[1] / 2;
  const int G = out_size / CLS;
  const int* row = eidx;
  const int* col = eidx + E;

  int bshift = 10;
  while ((1 << bshift) < E / NBKT + 32768) ++bshift;
  const long TS = (long)(N + 1) * 128;  // per-class slice-table stride (floats)
  const long ZS = (long)N * 128;        // per-class row-major stride (floats)

  char* ws = (char*)d_ws;
  size_t off = 0;
  auto alloc = [&](size_t bytes) -> void* {
    void* p = ws + off;
    off += (bytes + 255) & ~(size_t)255;
    return p;
  };
  float* Zall = (float*)alloc((size_t)CLS * ZS * 4);
  float* Tall = (float*)alloc((size_t)CLS * TS * 4);
  unsigned short* srcs = (unsigned short*)alloc(((size_t)E + 16 * (size_t)N + 64) * 2);
  int* cnt    = (int*)alloc(((size_t)N * 2 + NBKT) * 4);
  int* fillc  = cnt + N;
  int* bfill  = cnt + 2 * N;
  int* rptr2  = (int*)alloc((size_t)(N + 1) * 4);
  float* dinv = (float*)alloc((size_t)N * 4);
  unsigned* pairs = (unsigned*)Tall;  // alias: dead before k_zsent/k_scale
  (void)ws_size; (void)n_in;

  hipMemsetAsync(cnt, 0, ((size_t)N * 2 + NBKT) * 4, stream);
  const int eb = (E + 255) / 256;
  const int nb = (N + 255) / 256;
  k_count<<<eb, 256, 0, stream>>>(col, cnt, E);
  k_exscan<<<1, 1024, 0, stream>>>(cnt, rptr2, N);
  k_prep<<<nb, 256, 0, stream>>>(cnt, rptr2, dinv, srcs, N);
  k_bin<<<1024, 256, 0, stream>>>(row, col, bfill, pairs, E, (float)NBKT / (float)N, bshift);
  k_fill2<<<1024, 256, 0, stream>>>(pairs, bfill, rptr2, fillc, srcs, bshift);
  k_zsent<<<2, 256, 0, stream>>>(Tall, N);

  const int NB64 = (N + 63) / 64;
  const int gb = (N + 127) / 128;
  float* Z0 = Zall;

  // shared layer 0
  k_scale<<<dim3(NB64, 8), 256, 0, stream>>>(x, dinv, Tall, N);
  k_gather<<<dim3(NB64 * 8, 1), 256, 0, stream>>>(Tall, 0L, rptr2, srcs, dinv, Z0, 0L, N);

  // layer 1 (A shared across classes)
  k_gemm3<0><<<dim3(gb, CLS), 256, 0, stream>>>(Z0, 0L, conv_w + 0 * D * D,
                                                conv_b + 0 * D, dinv, Tall, TS, N);
  k_gather<<<dim3(NB64 * 8, CLS), 256, 0, stream>>>(Tall, TS, rptr2, srcs, dinv, Zall, ZS, N);

  // layer 2
  k_gemm3<0><<<dim3(gb, CLS), 256, 0, stream>>>(Zall, ZS, conv_w + 1 * D * D,
                                                conv_b + 1 * D, dinv, Tall, TS, N);
  k_gather<<<dim3(NB64 * 8, CLS), 256, 0, stream>>>(Tall, TS, rptr2, srcs, dinv, Zall, ZS, N);

  // layer 3 -> H (row-major, stored in the table slots)
  k_gemm3<1><<<dim3(gb, CLS), 256, 0, stream>>>(Zall, ZS, conv_w + 2 * D * D,
                                                conv_b + 2 * D, dinv, Tall, TS, N);

  // heads
  k_head<<<dim3(G, CLS), 128, 0, stream>>>(Tall, TS, batch, N,
                                           lin1_w, lin1_b, lin2_w, lin2_b, out, G);
}

// Round 12
// 909.233 us; speedup vs baseline: 3.3998x; 1.0138x over previous
//
#include <hip/hip_runtime.h>

#define D 128
#define CLS 3
#define LAY 3
#define NBKT 8

// exclusive scan of PADDED counts: pad(cnt) = (cnt+15)&~15  -> rptr2
__global__ __launch_bounds__(1024) void k_exscan(const int* __restrict__ cnt,
                                                 int* __restrict__ ptr, int n) {
  __shared__ int wsum[16];
  __shared__ int s_carry;
  const int tid = threadIdx.x;
  const int lane = tid & 63, wid = tid >> 6;
  if (tid == 0) s_carry = 0;
  __syncthreads();
  for (int base = 0; base < n; base += 1024) {
    int i = base + tid;
    int v = (i < n) ? ((cnt[i] + 15) & ~15) : 0;
    int s = v;
#pragma unroll
    for (int off = 1; off < 64; off <<= 1) {
      int t = __shfl_up(s, off, 64);
      if (lane >= off) s += t;
    }
    if (lane == 63) wsum[wid] = s;
    __syncthreads();
    if (wid == 0 && lane < 16) {
      int ws = wsum[lane];
#pragma unroll
      for (int off = 1; off < 16; off <<= 1) {
        int t = __shfl_up(ws, off, 16);
        if (lane >= off) ws += t;
      }
      wsum[lane] = ws;
    }
    __syncthreads();
    int carry = s_carry;
    int woff = wid ? wsum[wid - 1] : 0;
    if (i < n) ptr[i] = carry + woff + (s - v);
    __syncthreads();
    if (tid == 1023) s_carry = carry + wsum[15];
    __syncthreads();
  }
  if (tid == 0) ptr[n] = s_carry;
}

// dinv + fill CSR padding slots with sentinel N
__global__ void k_prep(const int* __restrict__ cnt, const int* __restrict__ rptr2,
                       float* __restrict__ dinv, unsigned short* __restrict__ srcs, int N) {
  int i = blockIdx.x * blockDim.x + threadIdx.x;
  if (i < N) {
    dinv[i] = rsqrtf((float)(cnt[i] + 1));
    int e = rptr2[i] + cnt[i], e1 = rptr2[i + 1];
    for (; e < e1; ++e) srcs[e] = (unsigned short)N;  // sentinel -> zero row
  }
}

// phase A: per-node degree count + bin edges into 8 col-range buckets (streaming writes)
__global__ __launch_bounds__(256) void k_bin(const int* __restrict__ row,
                                             const int* __restrict__ col,
                                             int* __restrict__ cnt,
                                             int* __restrict__ bfill,
                                             unsigned* __restrict__ pairs,
                                             int E, float bscale, int bshift) {
  __shared__ int lh[NBKT], gbase[NBKT], lcur[NBKT];
  const int tid = threadIdx.x;
  const int chunk = (E + gridDim.x - 1) / gridDim.x;
  const int s0 = blockIdx.x * chunk;
  const int s1 = min(s0 + chunk, E);
  if (tid < NBKT) lh[tid] = 0;
  __syncthreads();
  for (int e = s0 + tid; e < s1; e += 256) {
    int c = col[e];
    atomicAdd(&cnt[c], 1);  // folded k_count
    int b = min(NBKT - 1, (int)((float)c * bscale));
    atomicAdd(&lh[b], 1);
  }
  __syncthreads();
  if (tid < NBKT) {
    gbase[tid] = atomicAdd(&bfill[tid], lh[tid]);
    lcur[tid] = 0;
  }
  __syncthreads();
  for (int e = s0 + tid; e < s1; e += 256) {
    int c = col[e], r = row[e];
    int b = min(NBKT - 1, (int)((float)c * bscale));
    int off = atomicAdd(&lcur[b], 1);
    pairs[(b << bshift) + gbase[b] + off] = ((unsigned)r << 16) | (unsigned)c;
  }
}

// phase B: XCD-affine scatter into padded CSR (bucket b only on blocks with blockIdx&7==b)
__global__ __launch_bounds__(256) void k_fill2(const unsigned* __restrict__ pairs,
                                               const int* __restrict__ bfill,
                                               const int* __restrict__ rptr2,
                                               int* __restrict__ fillc,
                                               unsigned short* __restrict__ srcs,
                                               int bshift) {
  const int b = blockIdx.x & 7;
  const int bi = blockIdx.x >> 3;
  const int cap = bfill[b];
  const int stride = (gridDim.x >> 3) * blockDim.x;
  const unsigned* __restrict__ bp = pairs + ((size_t)b << bshift);
  for (int idx = bi * blockDim.x + threadIdx.x; idx < cap; idx += stride) {
    unsigned p = bp[idx];
    int c = (int)(p & 0xFFFFu);
    int pos = rptr2[c] + atomicAdd(&fillc[c], 1);
    srcs[pos] = (unsigned short)(p >> 16);
  }
}

// zero the 8 sentinel rows of each of the 3 slice tables
__global__ void k_zsent(float* __restrict__ Tall, int N) {
  int t = blockIdx.x * blockDim.x + threadIdx.x;   // 3*8*16 = 384
  if (t < CLS * 8 * 16) {
    int c = t / 128, rem = t % 128;
    int s = rem / 16, f = rem % 16;
    Tall[((size_t)c * 8 + s) * (size_t)(N + 1) * 16 + (size_t)N * 16 + f] = 0.f;
  }
}

// ---- T0 = x * dinv, slice-major [8][N+1][16] ----
__global__ __launch_bounds__(256) void k_scale(const float* __restrict__ x,
                                               const float* __restrict__ dinv,
                                               float* __restrict__ T, int N) {
  const int s = blockIdx.y;
  const int i = blockIdx.x * 64 + (threadIdx.x >> 2);
  const int f = threadIdx.x & 3;
  if (i < N) {
    float4 v = *(const float4*)&x[(size_t)i * 128 + s * 16 + f * 4];
    float d = dinv[i];
    v.x *= d; v.y *= d; v.z *= d; v.w *= d;
    *(float4*)&T[((size_t)s * (N + 1) + i) * 16 + f * 4] = v;
  }
}

// ---- XCD-sliced gather, fused over classes (blockIdx.y = class) ----
// 16 NAMED float4 registers hold 16 in-flight gathers (latency hiding);
// sched_barrier(0) pins all loads before the accumulate block.
__global__ __launch_bounds__(256, 4) void k_gather(const float* __restrict__ Tbase, long tstride,
                                                   const int* __restrict__ rptr2,
                                                   const unsigned short* __restrict__ srcs,
                                                   const float* __restrict__ dinv,
                                                   float* __restrict__ Zbase, long zstride,
                                                   int N) {
  const int s = blockIdx.x & 7;
  const int chunk = blockIdx.x >> 3;
  const int i = chunk * 64 + (threadIdx.x >> 2);
  const int f = threadIdx.x & 3;
  if (i >= N) return;
  const float* __restrict__ T = Tbase + (size_t)blockIdx.y * tstride;
  float* __restrict__ Z = Zbase + (size_t)blockIdx.y * zstride;
  const float4* __restrict__ Ts = (const float4*)(T + (size_t)s * (N + 1) * 16);
  const int e0 = rptr2[i], e1 = rptr2[i + 1];
  float4 a0 = Ts[(size_t)i * 4 + f];  // self term
  float4 a1 = make_float4(0.f, 0.f, 0.f, 0.f);
  float4 a2 = make_float4(0.f, 0.f, 0.f, 0.f);
  float4 a3 = make_float4(0.f, 0.f, 0.f, 0.f);
  ushort4 q = make_ushort4(0, 0, 0, 0);
  if (e0 < e1) q = *(const ushort4*)(srcs + e0 + (f << 2));
  for (int eb = e0; eb < e1; eb += 16) {
    ushort4 qn = q;
    if (eb + 16 < e1) qn = *(const ushort4*)(srcs + eb + 16 + (f << 2));
    const int j0  = __shfl((int)q.x, 0, 4);
    const int j1  = __shfl((int)q.y, 0, 4);
    const int j2  = __shfl((int)q.z, 0, 4);
    const int j3  = __shfl((int)q.w, 0, 4);
    const int j4  = __shfl((int)q.x, 1, 4);
    const int j5  = __shfl((int)q.y, 1, 4);
    const int j6  = __shfl((int)q.z, 1, 4);
    const int j7  = __shfl((int)q.w, 1, 4);
    const int j8  = __shfl((int)q.x, 2, 4);
    const int j9  = __shfl((int)q.y, 2, 4);
    const int j10 = __shfl((int)q.z, 2, 4);
    const int j11 = __shfl((int)q.w, 2, 4);
    const int j12 = __shfl((int)q.x, 3, 4);
    const int j13 = __shfl((int)q.y, 3, 4);
    const int j14 = __shfl((int)q.z, 3, 4);
    const int j15 = __shfl((int)q.w, 3, 4);
    const float4 v0  = Ts[(size_t)j0  * 4 + f];
    const float4 v1  = Ts[(size_t)j1  * 4 + f];
    const float4 v2  = Ts[(size_t)j2  * 4 + f];
    const float4 v3  = Ts[(size_t)j3  * 4 + f];
    const float4 v4  = Ts[(size_t)j4  * 4 + f];
    const float4 v5  = Ts[(size_t)j5  * 4 + f];
    const float4 v6  = Ts[(size_t)j6  * 4 + f];
    const float4 v7  = Ts[(size_t)j7  * 4 + f];
    const float4 v8  = Ts[(size_t)j8  * 4 + f];
    const float4 v9  = Ts[(size_t)j9  * 4 + f];
    const float4 v10 = Ts[(size_t)j10 * 4 + f];
    const float4 v11 = Ts[(size_t)j11 * 4 + f];
    const float4 v12 = Ts[(size_t)j12 * 4 + f];
    const float4 v13 = Ts[(size_t)j13 * 4 + f];
    const float4 v14 = Ts[(size_t)j14 * 4 + f];
    const float4 v15 = Ts[(size_t)j15 * 4 + f];
    __builtin_amdgcn_sched_barrier(0);  // all 16 gathers issued before consumption
    a0.x += v0.x;  a0.y += v0.y;  a0.z += v0.z;  a0.w += v0.w;
    a1.x += v1.x;  a1.y += v1.y;  a1.z += v1.z;  a1.w += v1.w;
    a2.x += v2.x;  a2.y += v2.y;  a2.z += v2.z;  a2.w += v2.w;
    a3.x += v3.x;  a3.y += v3.y;  a3.z += v3.z;  a3.w += v3.w;
    a0.x += v4.x;  a0.y += v4.y;  a0.z += v4.z;  a0.w += v4.w;
    a1.x += v5.x;  a1.y += v5.y;  a1.z += v5.z;  a1.w += v5.w;
    a2.x += v6.x;  a2.y += v6.y;  a2.z += v6.z;  a2.w += v6.w;
    a3.x += v7.x;  a3.y += v7.y;  a3.z += v7.z;  a3.w += v7.w;
    a0.x += v8.x;  a0.y += v8.y;  a0.z += v8.z;  a0.w += v8.w;
    a1.x += v9.x;  a1.y += v9.y;  a1.z += v9.z;  a1.w += v9.w;
    a2.x += v10.x; a2.y += v10.y; a2.z += v10.z; a2.w += v10.w;
    a3.x += v11.x; a3.y += v11.y; a3.z += v11.z; a3.w += v11.w;
    a0.x += v12.x; a0.y += v12.y; a0.z += v12.z; a0.w += v12.w;
    a1.x += v13.x; a1.y += v13.y; a1.z += v13.z; a1.w += v13.w;
    a2.x += v14.x; a2.y += v14.y; a2.z += v14.z; a2.w += v14.w;
    a3.x += v15.x; a3.y += v15.y; a3.z += v15.z; a3.w += v15.w;
    q = qn;
  }
  const float d = dinv[i];
  float4 r;
  r.x = (a0.x + a1.x + a2.x + a3.x) * d;
  r.y = (a0.y + a1.y + a2.y + a3.y) * d;
  r.z = (a0.z + a1.z + a2.z + a3.z) * d;
  r.w = (a0.w + a1.w + a2.w + a3.w) * d;
  *(float4*)&Z[(size_t)i * 128 + s * 16 + f * 4] = r;
}

// ---- batched 3-class GEMM + bias + L2-norm + ReLU (+dinv, slice-major) ----
// Round-9 version (proven 79us): 128x128 tile, BK=16, conflict-free A reads
// (rows split 4+4 at distance 64), red[] aliased over As/Ws (16 KB LDS).
template <int MODE>
__global__ __launch_bounds__(256, 4) void k_gemm3(const float* __restrict__ Abase, long astride,
                                                  const float* __restrict__ Wl,
                                                  const float* __restrict__ bl,
                                                  const float* __restrict__ dinv,
                                                  float* __restrict__ Obase, long ostride,
                                                  int N) {
  __shared__ __align__(16) char smem_raw[16 * 128 * 4 * 2];  // 16 KB
  float* __restrict__ Asf = (float*)smem_raw;                // [16][128]
  float* __restrict__ Wsf = (float*)(smem_raw + 8192);       // [16][128]
  typedef float redrow[17];
  redrow* red = (redrow*)smem_raw;                           // [128][17], epilogue only

  const int c = blockIdx.y;
  const float* __restrict__ A = Abase + (size_t)c * astride;
  const float* __restrict__ W = Wl + (size_t)c * (LAY * D * D);
  const float* __restrict__ bias = bl + (size_t)c * (LAY * D);
  float* __restrict__ Out = Obase + (size_t)c * ostride;

  const int tid = threadIdx.x;
  const int tr = tid & 15;
  const int tc = tid >> 4;
  const int m0 = blockIdx.x * 128;
  float acc[8][8];
#pragma unroll
  for (int i = 0; i < 8; ++i)
#pragma unroll
    for (int j = 0; j < 8; ++j) acc[i][j] = 0.f;

  const int lr = tid >> 1;       // 0..127 A row in tile
  const int lq = tid & 1;        // k half
  const int gr_l = m0 + lr;

  for (int kc = 0; kc < 128; kc += 16) {
    float4 va0 = make_float4(0.f, 0.f, 0.f, 0.f), va1 = va0;
    if (gr_l < N) {
      va0 = *(const float4*)&A[(size_t)gr_l * 128 + kc + lq * 8];
      va1 = *(const float4*)&A[(size_t)gr_l * 128 + kc + lq * 8 + 4];
    }
    Asf[(lq * 8 + 0) * 128 + lr] = va0.x;
    Asf[(lq * 8 + 1) * 128 + lr] = va0.y;
    Asf[(lq * 8 + 2) * 128 + lr] = va0.z;
    Asf[(lq * 8 + 3) * 128 + lr] = va0.w;
    Asf[(lq * 8 + 4) * 128 + lr] = va1.x;
    Asf[(lq * 8 + 5) * 128 + lr] = va1.y;
    Asf[(lq * 8 + 6) * 128 + lr] = va1.z;
    Asf[(lq * 8 + 7) * 128 + lr] = va1.w;
#pragma unroll
    for (int it = 0; it < 2; ++it) {
      const int lin = tid + it * 256;
      const int kr = lin >> 5;
      const int cq = lin & 31;
      *(float4*)&Wsf[kr * 128 + cq * 4] = *(const float4*)&W[(size_t)(kc + kr) * 128 + cq * 4];
    }
    __syncthreads();
#pragma unroll
    for (int kk = 0; kk < 16; ++kk) {
      float4 a4 = *(const float4*)&Asf[kk * 128 + tr * 4];
      float4 a4b = *(const float4*)&Asf[kk * 128 + 64 + tr * 4];
      float4 b4 = *(const float4*)&Wsf[kk * 128 + tc * 8];
      float4 b4b = *(const float4*)&Wsf[kk * 128 + tc * 8 + 4];
      float a[8] = {a4.x, a4.y, a4.z, a4.w, a4b.x, a4b.y, a4b.z, a4b.w};
      float b[8] = {b4.x, b4.y, b4.z, b4.w, b4b.x, b4b.y, b4b.z, b4b.w};
#pragma unroll
      for (int i = 0; i < 8; ++i)
#pragma unroll
        for (int j = 0; j < 8; ++j) acc[i][j] = fmaf(a[i], b[j], acc[i][j]);
    }
    __syncthreads();
  }

  // epilogue: bias, row L2-norm, relu, (dinv), store. rows: tr*4+i and 64+tr*4+(i-4).
  const int c0 = tc * 8;
  float bj[8];
#pragma unroll
  for (int j = 0; j < 8; ++j) bj[j] = bias[c0 + j];
#pragma unroll
  for (int i = 0; i < 8; ++i) {
    const int r = (i < 4) ? (tr * 4 + i) : (64 + tr * 4 + i - 4);
    float rs = 0.f;
#pragma unroll
    for (int j = 0; j < 8; ++j) {
      acc[i][j] += bj[j];
      rs = fmaf(acc[i][j], acc[i][j], rs);
    }
    red[r][tc] = rs;
  }
  __syncthreads();
#pragma unroll
  for (int i = 0; i < 8; ++i) {
    const int r = (i < 4) ? (tr * 4 + i) : (64 + tr * 4 + i - 4);
    const int gr = m0 + r;
    if (gr >= N) continue;
    float rsum = 0.f;
#pragma unroll
    for (int q = 0; q < 16; ++q) rsum += red[r][q];
    float sc = 1.0f / fmaxf(sqrtf(rsum), 1e-12f);
    if (MODE == 0) sc *= dinv[gr];
    float4 o0, o1;
    o0.x = fmaxf(acc[i][0] * sc, 0.f);
    o0.y = fmaxf(acc[i][1] * sc, 0.f);
    o0.z = fmaxf(acc[i][2] * sc, 0.f);
    o0.w = fmaxf(acc[i][3] * sc, 0.f);
    o1.x = fmaxf(acc[i][4] * sc, 0.f);
    o1.y = fmaxf(acc[i][5] * sc, 0.f);
    o1.z = fmaxf(acc[i][6] * sc, 0.f);
    o1.w = fmaxf(acc[i][7] * sc, 0.f);
    if (MODE == 0) {
      size_t base = ((size_t)(tc >> 1) * (N + 1) + gr) * 16 + (tc & 1) * 8;
      *(float4*)&Out[base] = o0;
      *(float4*)&Out[base + 4] = o1;
    } else {
      *(float4*)&Out[(size_t)gr * 128 + c0] = o0;
      *(float4*)&Out[(size_t)gr * 128 + c0 + 4] = o1;
    }
  }
}

// ------------- batched head: pool + lin1 + ReLU + lin2 (blockIdx.y = class) -------------
__device__ __forceinline__ int lowerb(const int* __restrict__ a, int n, int v) {
  int lo = 0, hi = n;
  while (lo < hi) {
    int m = (lo + hi) >> 1;
    if (a[m] < v) lo = m + 1; else hi = m;
  }
  return lo;
}

__global__ __launch_bounds__(128) void k_head(const float* __restrict__ Hall, long hstride,
                                              const int* __restrict__ batch, int N,
                                              const float* __restrict__ l1w,
                                              const float* __restrict__ l1b,
                                              const float* __restrict__ l2w,
                                              const float* __restrict__ l2b,
                                              float* __restrict__ out, int G) {
  const int g = blockIdx.x;
  const int c = blockIdx.y;
  const int t = threadIdx.x;
  const float* __restrict__ h = Hall + (size_t)c * hstride;
  const float* __restrict__ w1 = l1w + (size_t)c * D * D;
  const float* __restrict__ w2 = l2w + (size_t)c * D;
  int lo = lowerb(batch, N, g);
  int hi = lowerb(batch, N, g + 1);
  float p = 0.f;
  for (int i = lo; i < hi; ++i) p += h[(size_t)i * 128 + t];
  __shared__ float pl[128];
  pl[t] = p;
  __syncthreads();
  float z = l1b[(size_t)c * D + t];
#pragma unroll 8
  for (int k = 0; k < 128; ++k) z = fmaf(pl[k], w1[k * 128 + t], z);
  z = fmaxf(z, 0.f);
  float o = z * w2[t];
#pragma unroll
  for (int off = 32; off > 0; off >>= 1) o += __shfl_xor(o, off, 64);
  __shared__ float s2[2];
  if ((t & 63) == 0) s2[t >> 6] = o;
  __syncthreads();
  if (t == 0) out[(size_t)g * CLS + c] = s2[0] + s2[1] + l2b[c];
}

extern "C" void kernel_launch(void* const* d_in, const int* in_sizes, int n_in,
                              void* d_out, int out_size, void* d_ws, size_t ws_size,
                              hipStream_t stream) {
  const float* x = (const float*)d_in[0];
  const int* eidx = (const int*)d_in[1];
  const int* batch = (const int*)d_in[2];
  const float* conv_w = (const float*)d_in[3];
  const float* conv_b = (const float*)d_in[4];
  const float* lin1_w = (const float*)d_in[5];
  const float* lin1_b = (const float*)d_in[6];
  const float* lin2_w = (const float*)d_in[7];
  const float* lin2_b = (const float*)d_in[8];
  float* out = (float*)d_out;

  const int N = in_sizes[0] / D;
  const int E = in_sizes[1] / 2;
  const int G = out_size / CLS;
  const int* row = eidx;
  const int* col = eidx + E;

  int bshift = 10;
  while ((1 << bshift) < E / NBKT + 32768) ++bshift;
  const long TS = (long)(N + 1) * 128;  // per-class slice-table stride (floats)
  const long ZS = (long)N * 128;        // per-class row-major stride (floats)

  char* ws = (char*)d_ws;
  size_t off = 0;
  auto alloc = [&](size_t bytes) -> void* {
    void* p = ws + off;
    off += (bytes + 255) & ~(size_t)255;
    return p;
  };
  float* Zall = (float*)alloc((size_t)CLS * ZS * 4);
  float* Tall = (float*)alloc((size_t)CLS * TS * 4);
  unsigned short* srcs = (unsigned short*)alloc(((size_t)E + 16 * (size_t)N + 64) * 2);
  int* cnt    = (int*)alloc(((size_t)N * 2 + NBKT) * 4);
  int* fillc  = cnt + N;
  int* bfill  = cnt + 2 * N;
  int* rptr2  = (int*)alloc((size_t)(N + 1) * 4);
  float* dinv = (float*)alloc((size_t)N * 4);
  unsigned* pairs = (unsigned*)Tall;  // alias: dead before k_zsent/k_scale
  (void)ws_size; (void)n_in;

  hipMemsetAsync(cnt, 0, ((size_t)N * 2 + NBKT) * 4, stream);
  const int nb = (N + 255) / 256;
  k_bin<<<1024, 256, 0, stream>>>(row, col, cnt, bfill, pairs, E, (float)NBKT / (float)N, bshift);
  k_exscan<<<1, 1024, 0, stream>>>(cnt, rptr2, N);
  k_prep<<<nb, 256, 0, stream>>>(cnt, rptr2, dinv, srcs, N);
  k_fill2<<<1024, 256, 0, stream>>>(pairs, bfill, rptr2, fillc, srcs, bshift);
  k_zsent<<<2, 256, 0, stream>>>(Tall, N);

  const int NB64 = (N + 63) / 64;
  const int gb = (N + 127) / 128;
  float* Z0 = Zall;

  // shared layer 0
  k_scale<<<dim3(NB64, 8), 256, 0, stream>>>(x, dinv, Tall, N);
  k_gather<<<dim3(NB64 * 8, 1), 256, 0, stream>>>(Tall, 0L, rptr2, srcs, dinv, Z0, 0L, N);

  // layer 1 (A shared across classes)
  k_gemm3<0><<<dim3(gb, CLS), 256, 0, stream>>>(Z0, 0L, conv_w + 0 * D * D,
                                                conv_b + 0 * D, dinv, Tall, TS, N);
  k_gather<<<dim3(NB64 * 8, CLS), 256, 0, stream>>>(Tall, TS, rptr2, srcs, dinv, Zall, ZS, N);

  // layer 2
  k_gemm3<0><<<dim3(gb, CLS), 256, 0, stream>>>(Zall, ZS, conv_w + 1 * D * D,
                                                conv_b + 1 * D, dinv, Tall, TS, N);
  k_gather<<<dim3(NB64 * 8, CLS), 256, 0, stream>>>(Tall, TS, rptr2, srcs, dinv, Zall, ZS, N);

  // layer 3 -> H (row-major, stored in the table slots)
  k_gemm3<1><<<dim3(gb, CLS), 256, 0, stream>>>(Zall, ZS, conv_w + 2 * D * D,
                                                conv_b + 2 * D, dinv, Tall, TS, N);

  // heads
  k_head<<<dim3(G, CLS), 128, 0, stream>>>(Tall, TS, batch, N,
                                           lin1_w, lin1_b, lin2_w, lin2_b, out, G);
}

// Round 13
// 898.834 us; speedup vs baseline: 3.4391x; 1.0116x over previous
//
#include <hip/hip_runtime.h>

#define D 128
#define CLS 3
#define LAY 3
#define NBKT 8

typedef __attribute__((ext_vector_type(4))) float evf4;

// exclusive scan of PADDED counts: pad(cnt) = (cnt+15)&~15  -> rptr2
__global__ __launch_bounds__(1024) void k_exscan(const int* __restrict__ cnt,
                                                 int* __restrict__ ptr, int n) {
  __shared__ int wsum[16];
  __shared__ int s_carry;
  const int tid = threadIdx.x;
  const int lane = tid & 63, wid = tid >> 6;
  if (tid == 0) s_carry = 0;
  __syncthreads();
  for (int base = 0; base < n; base += 1024) {
    int i = base + tid;
    int v = (i < n) ? ((cnt[i] + 15) & ~15) : 0;
    int s = v;
#pragma unroll
    for (int off = 1; off < 64; off <<= 1) {
      int t = __shfl_up(s, off, 64);
      if (lane >= off) s += t;
    }
    if (lane == 63) wsum[wid] = s;
    __syncthreads();
    if (wid == 0 && lane < 16) {
      int ws = wsum[lane];
#pragma unroll
      for (int off = 1; off < 16; off <<= 1) {
        int t = __shfl_up(ws, off, 16);
        if (lane >= off) ws += t;
      }
      wsum[lane] = ws;
    }
    __syncthreads();
    int carry = s_carry;
    int woff = wid ? wsum[wid - 1] : 0;
    if (i < n) ptr[i] = carry + woff + (s - v);
    __syncthreads();
    if (tid == 1023) s_carry = carry + wsum[15];
    __syncthreads();
  }
  if (tid == 0) ptr[n] = s_carry;
}

// dinv + fill CSR padding slots with sentinel N
__global__ void k_prep(const int* __restrict__ cnt, const int* __restrict__ rptr2,
                       float* __restrict__ dinv, unsigned short* __restrict__ srcs, int N) {
  int i = blockIdx.x * blockDim.x + threadIdx.x;
  if (i < N) {
    dinv[i] = rsqrtf((float)(cnt[i] + 1));
    int e = rptr2[i] + cnt[i], e1 = rptr2[i + 1];
    for (; e < e1; ++e) srcs[e] = (unsigned short)N;  // sentinel -> zero row
  }
}

// phase A: per-node degree count + bin edges into 8 col-range buckets (streaming writes)
__global__ __launch_bounds__(256) void k_bin(const int* __restrict__ row,
                                             const int* __restrict__ col,
                                             int* __restrict__ cnt,
                                             int* __restrict__ bfill,
                                             unsigned* __restrict__ pairs,
                                             int E, float bscale, int bshift) {
  __shared__ int lh[NBKT], gbase[NBKT], lcur[NBKT];
  const int tid = threadIdx.x;
  const int chunk = (E + gridDim.x - 1) / gridDim.x;
  const int s0 = blockIdx.x * chunk;
  const int s1 = min(s0 + chunk, E);
  if (tid < NBKT) lh[tid] = 0;
  __syncthreads();
  for (int e = s0 + tid; e < s1; e += 256) {
    int c = col[e];
    atomicAdd(&cnt[c], 1);  // folded k_count
    int b = min(NBKT - 1, (int)((float)c * bscale));
    atomicAdd(&lh[b], 1);
  }
  __syncthreads();
  if (tid < NBKT) {
    gbase[tid] = atomicAdd(&bfill[tid], lh[tid]);
    lcur[tid] = 0;
  }
  __syncthreads();
  for (int e = s0 + tid; e < s1; e += 256) {
    int c = col[e], r = row[e];
    int b = min(NBKT - 1, (int)((float)c * bscale));
    int off = atomicAdd(&lcur[b], 1);
    pairs[(b << bshift) + gbase[b] + off] = ((unsigned)r << 16) | (unsigned)c;
  }
}

// phase B: XCD-affine scatter into padded CSR (bucket b only on blocks with blockIdx&7==b)
__global__ __launch_bounds__(256) void k_fill2(const unsigned* __restrict__ pairs,
                                               const int* __restrict__ bfill,
                                               const int* __restrict__ rptr2,
                                               int* __restrict__ fillc,
                                               unsigned short* __restrict__ srcs,
                                               int bshift) {
  const int b = blockIdx.x & 7;
  const int bi = blockIdx.x >> 3;
  const int cap = bfill[b];
  const int stride = (gridDim.x >> 3) * blockDim.x;
  const unsigned* __restrict__ bp = pairs + ((size_t)b << bshift);
  for (int idx = bi * blockDim.x + threadIdx.x; idx < cap; idx += stride) {
    unsigned p = bp[idx];
    int c = (int)(p & 0xFFFFu);
    int pos = rptr2[c] + atomicAdd(&fillc[c], 1);
    srcs[pos] = (unsigned short)(p >> 16);
  }
}

// zero the 8 sentinel rows of each of the 3 slice tables
__global__ void k_zsent(float* __restrict__ Tall, int N) {
  int t = blockIdx.x * blockDim.x + threadIdx.x;   // 3*8*16 = 384
  if (t < CLS * 8 * 16) {
    int c = t / 128, rem = t % 128;
    int s = rem / 16, f = rem % 16;
    Tall[((size_t)c * 8 + s) * (size_t)(N + 1) * 16 + (size_t)N * 16 + f] = 0.f;
  }
}

// ---- T0 = x * dinv, slice-major [8][N+1][16] ----
__global__ __launch_bounds__(256) void k_scale(const float* __restrict__ x,
                                               const float* __restrict__ dinv,
                                               float* __restrict__ T, int N) {
  const int s = blockIdx.y;
  const int i = blockIdx.x * 64 + (threadIdx.x >> 2);
  const int f = threadIdx.x & 3;
  if (i < N) {
    float4 v = *(const float4*)&x[(size_t)i * 128 + s * 16 + f * 4];
    float d = dinv[i];
    v.x *= d; v.y *= d; v.z *= d; v.w *= d;
    *(float4*)&T[((size_t)s * (N + 1) + i) * 16 + f * 4] = v;
  }
}

// ---- XCD-sliced gather, fused over classes (blockIdx.y = class) ----
// Per-lane direct index reads (no cross-lane shuffles), 16 gathers forced live
// simultaneously via empty inline-asm liveness pin -> 16 lines in flight per wave.
__global__ __launch_bounds__(256, 4) void k_gather(const float* __restrict__ Tbase, long tstride,
                                                   const int* __restrict__ rptr2,
                                                   const unsigned short* __restrict__ srcs,
                                                   const float* __restrict__ dinv,
                                                   float* __restrict__ Zbase, long zstride,
                                                   int N) {
  const int s = blockIdx.x & 7;
  const int chunk = blockIdx.x >> 3;
  const int i = chunk * 64 + (threadIdx.x >> 2);
  const int f = threadIdx.x & 3;
  if (i >= N) return;
  const float* __restrict__ T = Tbase + (size_t)blockIdx.y * tstride;
  float* __restrict__ Z = Zbase + (size_t)blockIdx.y * zstride;
  const evf4* __restrict__ Ts = (const evf4*)(T + (size_t)s * (N + 1) * 16);
  const int e0 = rptr2[i], e1 = rptr2[i + 1];
  evf4 a0 = Ts[(size_t)i * 4 + f];  // self term
  evf4 a1 = (evf4)0.f, a2 = (evf4)0.f, a3 = (evf4)0.f;
  uint4 I0 = make_uint4(0, 0, 0, 0), I1 = I0;
  if (e0 < e1) {
    I0 = *(const uint4*)(srcs + e0);      // edges 0..7  (u16 packed)
    I1 = *(const uint4*)(srcs + e0 + 8);  // edges 8..15
  }
  for (int eb = e0; eb < e1; eb += 16) {
    uint4 I0n = I0, I1n = I1;
    if (eb + 16 < e1) {
      I0n = *(const uint4*)(srcs + eb + 16);
      I1n = *(const uint4*)(srcs + eb + 24);
    }
    const int j0  = (int)(I0.x & 0xFFFFu), j1  = (int)(I0.x >> 16);
    const int j2  = (int)(I0.y & 0xFFFFu), j3  = (int)(I0.y >> 16);
    const int j4  = (int)(I0.z & 0xFFFFu), j5  = (int)(I0.z >> 16);
    const int j6  = (int)(I0.w & 0xFFFFu), j7  = (int)(I0.w >> 16);
    const int j8  = (int)(I1.x & 0xFFFFu), j9  = (int)(I1.x >> 16);
    const int j10 = (int)(I1.y & 0xFFFFu), j11 = (int)(I1.y >> 16);
    const int j12 = (int)(I1.z & 0xFFFFu), j13 = (int)(I1.z >> 16);
    const int j14 = (int)(I1.w & 0xFFFFu), j15 = (int)(I1.w >> 16);
    evf4 v0  = Ts[(size_t)j0  * 4 + f];
    evf4 v1  = Ts[(size_t)j1  * 4 + f];
    evf4 v2  = Ts[(size_t)j2  * 4 + f];
    evf4 v3  = Ts[(size_t)j3  * 4 + f];
    evf4 v4  = Ts[(size_t)j4  * 4 + f];
    evf4 v5  = Ts[(size_t)j5  * 4 + f];
    evf4 v6  = Ts[(size_t)j6  * 4 + f];
    evf4 v7  = Ts[(size_t)j7  * 4 + f];
    evf4 v8  = Ts[(size_t)j8  * 4 + f];
    evf4 v9  = Ts[(size_t)j9  * 4 + f];
    evf4 v10 = Ts[(size_t)j10 * 4 + f];
    evf4 v11 = Ts[(size_t)j11 * 4 + f];
    evf4 v12 = Ts[(size_t)j12 * 4 + f];
    evf4 v13 = Ts[(size_t)j13 * 4 + f];
    evf4 v14 = Ts[(size_t)j14 * 4 + f];
    evf4 v15 = Ts[(size_t)j15 * 4 + f];
    // Liveness pin: all 16 gathered values must be in distinct registers here,
    // so RA cannot serialize the loads; one vmcnt wait after 16 issued loads.
    asm volatile("" :: "v"(v0), "v"(v1), "v"(v2), "v"(v3),
                       "v"(v4), "v"(v5), "v"(v6), "v"(v7),
                       "v"(v8), "v"(v9), "v"(v10), "v"(v11),
                       "v"(v12), "v"(v13), "v"(v14), "v"(v15));
    __builtin_amdgcn_sched_barrier(0);
    a0 += v0;  a1 += v1;  a2 += v2;  a3 += v3;
    a0 += v4;  a1 += v5;  a2 += v6;  a3 += v7;
    a0 += v8;  a1 += v9;  a2 += v10; a3 += v11;
    a0 += v12; a1 += v13; a2 += v14; a3 += v15;
    I0 = I0n; I1 = I1n;
  }
  const float d = dinv[i];
  evf4 r = (a0 + a1 + a2 + a3) * d;
  *(evf4*)&Z[(size_t)i * 128 + s * 16 + f * 4] = r;
}

// ---- batched 3-class GEMM + bias + L2-norm + ReLU (+dinv, slice-major) ----
// Round-9 version (proven 79us): 128x128 tile, BK=16, conflict-free A reads
// (rows split 4+4 at distance 64), red[] aliased over As/Ws (16 KB LDS).
template <int MODE>
__global__ __launch_bounds__(256, 4) void k_gemm3(const float* __restrict__ Abase, long astride,
                                                  const float* __restrict__ Wl,
                                                  const float* __restrict__ bl,
                                                  const float* __restrict__ dinv,
                                                  float* __restrict__ Obase, long ostride,
                                                  int N) {
  __shared__ __align__(16) char smem_raw[16 * 128 * 4 * 2];  // 16 KB
  float* __restrict__ Asf = (float*)smem_raw;                // [16][128]
  float* __restrict__ Wsf = (float*)(smem_raw + 8192);       // [16][128]
  typedef float redrow[17];
  redrow* red = (redrow*)smem_raw;                           // [128][17], epilogue only

  const int c = blockIdx.y;
  const float* __restrict__ A = Abase + (size_t)c * astride;
  const float* __restrict__ W = Wl + (size_t)c * (LAY * D * D);
  const float* __restrict__ bias = bl + (size_t)c * (LAY * D);
  float* __restrict__ Out = Obase + (size_t)c * ostride;

  const int tid = threadIdx.x;
  const int tr = tid & 15;
  const int tc = tid >> 4;
  const int m0 = blockIdx.x * 128;
  float acc[8][8];
#pragma unroll
  for (int i = 0; i < 8; ++i)
#pragma unroll
    for (int j = 0; j < 8; ++j) acc[i][j] = 0.f;

  const int lr = tid >> 1;       // 0..127 A row in tile
  const int lq = tid & 1;        // k half
  const int gr_l = m0 + lr;

  for (int kc = 0; kc < 128; kc += 16) {
    float4 va0 = make_float4(0.f, 0.f, 0.f, 0.f), va1 = va0;
    if (gr_l < N) {
      va0 = *(const float4*)&A[(size_t)gr_l * 128 + kc + lq * 8];
      va1 = *(const float4*)&A[(size_t)gr_l * 128 + kc + lq * 8 + 4];
    }
    Asf[(lq * 8 + 0) * 128 + lr] = va0.x;
    Asf[(lq * 8 + 1) * 128 + lr] = va0.y;
    Asf[(lq * 8 + 2) * 128 + lr] = va0.z;
    Asf[(lq * 8 + 3) * 128 + lr] = va0.w;
    Asf[(lq * 8 + 4) * 128 + lr] = va1.x;
    Asf[(lq * 8 + 5) * 128 + lr] = va1.y;
    Asf[(lq * 8 + 6) * 128 + lr] = va1.z;
    Asf[(lq * 8 + 7) * 128 + lr] = va1.w;
#pragma unroll
    for (int it = 0; it < 2; ++it) {
      const int lin = tid + it * 256;
      const int kr = lin >> 5;
      const int cq = lin & 31;
      *(float4*)&Wsf[kr * 128 + cq * 4] = *(const float4*)&W[(size_t)(kc + kr) * 128 + cq * 4];
    }
    __syncthreads();
#pragma unroll
    for (int kk = 0; kk < 16; ++kk) {
      float4 a4 = *(const float4*)&Asf[kk * 128 + tr * 4];
      float4 a4b = *(const float4*)&Asf[kk * 128 + 64 + tr * 4];
      float4 b4 = *(const float4*)&Wsf[kk * 128 + tc * 8];
      float4 b4b = *(const float4*)&Wsf[kk * 128 + tc * 8 + 4];
      float a[8] = {a4.x, a4.y, a4.z, a4.w, a4b.x, a4b.y, a4b.z, a4b.w};
      float b[8] = {b4.x, b4.y, b4.z, b4.w, b4b.x, b4b.y, b4b.z, b4b.w};
#pragma unroll
      for (int i = 0; i < 8; ++i)
#pragma unroll
        for (int j = 0; j < 8; ++j) acc[i][j] = fmaf(a[i], b[j], acc[i][j]);
    }
    __syncthreads();
  }

  // epilogue: bias, row L2-norm, relu, (dinv), store. rows: tr*4+i and 64+tr*4+(i-4).
  const int c0 = tc * 8;
  float bj[8];
#pragma unroll
  for (int j = 0; j < 8; ++j) bj[j] = bias[c0 + j];
#pragma unroll
  for (int i = 0; i < 8; ++i) {
    const int r = (i < 4) ? (tr * 4 + i) : (64 + tr * 4 + i - 4);
    float rs = 0.f;
#pragma unroll
    for (int j = 0; j < 8; ++j) {
      acc[i][j] += bj[j];
      rs = fmaf(acc[i][j], acc[i][j], rs);
    }
    red[r][tc] = rs;
  }
  __syncthreads();
#pragma unroll
  for (int i = 0; i < 8; ++i) {
    const int r = (i < 4) ? (tr * 4 + i) : (64 + tr * 4 + i - 4);
    const int gr = m0 + r;
    if (gr >= N) continue;
    float rsum = 0.f;
#pragma unroll
    for (int q = 0; q < 16; ++q) rsum += red[r][q];
    float sc = 1.0f / fmaxf(sqrtf(rsum), 1e-12f);
    if (MODE == 0) sc *= dinv[gr];
    float4 o0, o1;
    o0.x = fmaxf(acc[i][0] * sc, 0.f);
    o0.y = fmaxf(acc[i][1] * sc, 0.f);
    o0.z = fmaxf(acc[i][2] * sc, 0.f);
    o0.w = fmaxf(acc[i][3] * sc, 0.f);
    o1.x = fmaxf(acc[i][4] * sc, 0.f);
    o1.y = fmaxf(acc[i][5] * sc, 0.f);
    o1.z = fmaxf(acc[i][6] * sc, 0.f);
    o1.w = fmaxf(acc[i][7] * sc, 0.f);
    if (MODE == 0) {
      size_t base = ((size_t)(tc >> 1) * (N + 1) + gr) * 16 + (tc & 1) * 8;
      *(float4*)&Out[base] = o0;
      *(float4*)&Out[base + 4] = o1;
    } else {
      *(float4*)&Out[(size_t)gr * 128 + c0] = o0;
      *(float4*)&Out[(size_t)gr * 128 + c0 + 4] = o1;
    }
  }
}

// ------------- batched head: pool + lin1 + ReLU + lin2 (blockIdx.y = class) -------------
__device__ __forceinline__ int lowerb(const int* __restrict__ a, int n, int v) {
  int lo = 0, hi = n;
  while (lo < hi) {
    int m = (lo + hi) >> 1;
    if (a[m] < v) lo = m + 1; else hi = m;
  }
  return lo;
}

__global__ __launch_bounds__(128) void k_head(const float* __restrict__ Hall, long hstride,
                                              const int* __restrict__ batch, int N,
                                              const float* __restrict__ l1w,
                                              const float* __restrict__ l1b,
                                              const float* __restrict__ l2w,
                                              const float* __restrict__ l2b,
                                              float* __restrict__ out, int G) {
  const int g = blockIdx.x;
  const int c = blockIdx.y;
  const int t = threadIdx.x;
  const float* __restrict__ h = Hall + (size_t)c * hstride;
  const float* __restrict__ w1 = l1w + (size_t)c * D * D;
  const float* __restrict__ w2 = l2w + (size_t)c * D;
  int lo = lowerb(batch, N, g);
  int hi = lowerb(batch, N, g + 1);
  float p = 0.f;
  for (int i = lo; i < hi; ++i) p += h[(size_t)i * 128 + t];
  __shared__ float pl[128];
  pl[t] = p;
  __syncthreads();
  float z = l1b[(size_t)c * D + t];
#pragma unroll 8
  for (int k = 0; k < 128; ++k) z = fmaf(pl[k], w1[k * 128 + t], z);
  z = fmaxf(z, 0.f);
  float o = z * w2[t];
#pragma unroll
  for (int off = 32; off > 0; off >>= 1) o += __shfl_xor(o, off, 64);
  __shared__ float s2[2];
  if ((t & 63) == 0) s2[t >> 6] = o;
  __syncthreads();
  if (t == 0) out[(size_t)g * CLS + c] = s2[0] + s2[1] + l2b[c];
}

extern "C" void kernel_launch(void* const* d_in, const int* in_sizes, int n_in,
                              void* d_out, int out_size, void* d_ws, size_t ws_size,
                              hipStream_t stream) {
  const float* x = (const float*)d_in[0];
  const int* eidx = (const int*)d_in[1];
  const int* batch = (const int*)d_in[2];
  const float* conv_w = (const float*)d_in[3];
  const float* conv_b = (const float*)d_in[4];
  const float* lin1_w = (const float*)d_in[5];
  const float* lin1_b = (const float*)d_in[6];
  const float* lin2_w = (const float*)d_in[7];
  const float* lin2_b = (const float*)d_in[8];
  float* out = (float*)d_out;

  const int N = in_sizes[0] / D;
  const int E = in_sizes[1] / 2;
  const int G = out_size / CLS;
  const int* row = eidx;
  const int* col = eidx + E;

  int bshift = 10;
  while ((1 << bshift) < E / NBKT + 32768) ++bshift;
  const long TS = (long)(N + 1) * 128;  // per-class slice-table stride (floats)
  const long ZS = (long)N * 128;        // per-class row-major stride (floats)

  char* ws = (char*)d_ws;
  size_t off = 0;
  auto alloc = [&](size_t bytes) -> void* {
    void* p = ws + off;
    off += (bytes + 255) & ~(size_t)255;
    return p;
  };
  float* Zall = (float*)alloc((size_t)CLS * ZS * 4);
  float* Tall = (float*)alloc((size_t)CLS * TS * 4);
  unsigned short* srcs = (unsigned short*)alloc(((size_t)E + 16 * (size_t)N + 64) * 2);
  int* cnt    = (int*)alloc(((size_t)N * 2 + NBKT) * 4);
  int* fillc  = cnt + N;
  int* bfill  = cnt + 2 * N;
  int* rptr2  = (int*)alloc((size_t)(N + 1) * 4);
  float* dinv = (float*)alloc((size_t)N * 4);
  unsigned* pairs = (unsigned*)Tall;  // alias: dead before k_zsent/k_scale
  (void)ws_size; (void)n_in;

  hipMemsetAsync(cnt, 0, ((size_t)N * 2 + NBKT) * 4, stream);
  const int nb = (N + 255) / 256;
  k_bin<<<1024, 256, 0, stream>>>(row, col, cnt, bfill, pairs, E, (float)NBKT / (float)N, bshift);
  k_exscan<<<1, 1024, 0, stream>>>(cnt, rptr2, N);
  k_prep<<<nb, 256, 0, stream>>>(cnt, rptr2, dinv, srcs, N);
  k_fill2<<<1024, 256, 0, stream>>>(pairs, bfill, rptr2, fillc, srcs, bshift);
  k_zsent<<<2, 256, 0, stream>>>(Tall, N);

  const int NB64 = (N + 63) / 64;
  const int gb = (N + 127) / 128;
  float* Z0 = Zall;

  // shared layer 0
  k_scale<<<dim3(NB64, 8), 256, 0, stream>>>(x, dinv, Tall, N);
  k_gather<<<dim3(NB64 * 8, 1), 256, 0, stream>>>(Tall, 0L, rptr2, srcs, dinv, Z0, 0L, N);

  // layer 1 (A shared across classes)
  k_gemm3<0><<<dim3(gb, CLS), 256, 0, stream>>>(Z0, 0L, conv_w + 0 * D * D,
                                                conv_b + 0 * D, dinv, Tall, TS, N);
  k_gather<<<dim3(NB64 * 8, CLS), 256, 0, stream>>>(Tall, TS, rptr2, srcs, dinv, Zall, ZS, N);

  // layer 2
  k_gemm3<0><<<dim3(gb, CLS), 256, 0, stream>>>(Zall, ZS, conv_w + 1 * D * D,
                                                conv_b + 1 * D, dinv, Tall, TS, N);
  k_gather<<<dim3(NB64 * 8, CLS), 256, 0, stream>>>(Tall, TS, rptr2, srcs, dinv, Zall, ZS, N);

  // layer 3 -> H (row-major, stored in the table slots)
  k_gemm3<1><<<dim3(gb, CLS), 256, 0, stream>>>(Zall, ZS, conv_w + 2 * D * D,
                                                conv_b + 2 * D, dinv, Tall, TS, N);

  // heads
  k_head<<<dim3(G, CLS), 128, 0, stream>>>(Tall, TS, batch, N,
                                           lin1_w, lin1_b, lin2_w, lin2_b, out, G);
}

// Round 14
// 876.181 us; speedup vs baseline: 3.5281x; 1.0259x over previous
//
#include <hip/hip_runtime.h>

#define D 128
#define CLS 3
#define LAY 3
#define NBKT 8

typedef __attribute__((ext_vector_type(4))) float evf4;
typedef __attribute__((ext_vector_type(8))) short bf16x8;
typedef __attribute__((ext_vector_type(4))) float f32x4;

__device__ __forceinline__ unsigned short bf16rne(float x) {
  unsigned b = __float_as_uint(x);
  unsigned r = b + 0x7FFFu + ((b >> 16) & 1u);
  return (unsigned short)(r >> 16);
}
__device__ __forceinline__ float bf16tof(unsigned short h) {
  return __uint_as_float(((unsigned)h) << 16);
}

// exclusive scan of PADDED counts: pad(cnt) = (cnt+15)&~15  -> rptr2
__global__ __launch_bounds__(1024) void k_exscan(const int* __restrict__ cnt,
                                                 int* __restrict__ ptr, int n) {
  __shared__ int wsum[16];
  __shared__ int s_carry;
  const int tid = threadIdx.x;
  const int lane = tid & 63, wid = tid >> 6;
  if (tid == 0) s_carry = 0;
  __syncthreads();
  for (int base = 0; base < n; base += 1024) {
    int i = base + tid;
    int v = (i < n) ? ((cnt[i] + 15) & ~15) : 0;
    int s = v;
#pragma unroll
    for (int off = 1; off < 64; off <<= 1) {
      int t = __shfl_up(s, off, 64);
      if (lane >= off) s += t;
    }
    if (lane == 63) wsum[wid] = s;
    __syncthreads();
    if (wid == 0 && lane < 16) {
      int ws = wsum[lane];
#pragma unroll
      for (int off = 1; off < 16; off <<= 1) {
        int t = __shfl_up(ws, off, 16);
        if (lane >= off) ws += t;
      }
      wsum[lane] = ws;
    }
    __syncthreads();
    int carry = s_carry;
    int woff = wid ? wsum[wid - 1] : 0;
    if (i < n) ptr[i] = carry + woff + (s - v);
    __syncthreads();
    if (tid == 1023) s_carry = carry + wsum[15];
    __syncthreads();
  }
  if (tid == 0) ptr[n] = s_carry;
}

// dinv + fill CSR padding slots with sentinel N
__global__ void k_prep(const int* __restrict__ cnt, const int* __restrict__ rptr2,
                       float* __restrict__ dinv, unsigned short* __restrict__ srcs, int N) {
  int i = blockIdx.x * blockDim.x + threadIdx.x;
  if (i < N) {
    dinv[i] = rsqrtf((float)(cnt[i] + 1));
    int e = rptr2[i] + cnt[i], e1 = rptr2[i + 1];
    for (; e < e1; ++e) srcs[e] = (unsigned short)N;  // sentinel -> zero row
  }
}

// phase A: per-node degree count + bin edges into 8 col-range buckets
__global__ __launch_bounds__(256) void k_bin(const int* __restrict__ row,
                                             const int* __restrict__ col,
                                             int* __restrict__ cnt,
                                             int* __restrict__ bfill,
                                             unsigned* __restrict__ pairs,
                                             int E, float bscale, int bshift) {
  __shared__ int lh[NBKT], gbase[NBKT], lcur[NBKT];
  const int tid = threadIdx.x;
  const int chunk = (E + gridDim.x - 1) / gridDim.x;
  const int s0 = blockIdx.x * chunk;
  const int s1 = min(s0 + chunk, E);
  if (tid < NBKT) lh[tid] = 0;
  __syncthreads();
  for (int e = s0 + tid; e < s1; e += 256) {
    int c = col[e];
    atomicAdd(&cnt[c], 1);
    int b = min(NBKT - 1, (int)((float)c * bscale));
    atomicAdd(&lh[b], 1);
  }
  __syncthreads();
  if (tid < NBKT) {
    gbase[tid] = atomicAdd(&bfill[tid], lh[tid]);
    lcur[tid] = 0;
  }
  __syncthreads();
  for (int e = s0 + tid; e < s1; e += 256) {
    int c = col[e], r = row[e];
    int b = min(NBKT - 1, (int)((float)c * bscale));
    int off = atomicAdd(&lcur[b], 1);
    pairs[(b << bshift) + gbase[b] + off] = ((unsigned)r << 16) | (unsigned)c;
  }
}

// phase B: XCD-affine scatter into padded CSR (bucket b on blocks with blockIdx&7==b)
__global__ __launch_bounds__(256) void k_fill2(const unsigned* __restrict__ pairs,
                                               const int* __restrict__ bfill,
                                               const int* __restrict__ rptr2,
                                               int* __restrict__ fillc,
                                               unsigned short* __restrict__ srcs,
                                               int bshift) {
  const int b = blockIdx.x & 7;
  const int bi = blockIdx.x >> 3;
  const int cap = bfill[b];
  const int stride = (gridDim.x >> 3) * blockDim.x;
  const unsigned* __restrict__ bp = pairs + ((size_t)b << bshift);
  for (int idx = bi * blockDim.x + threadIdx.x; idx < cap; idx += stride) {
    unsigned p = bp[idx];
    int c = (int)(p & 0xFFFFu);
    int pos = rptr2[c] + atomicAdd(&fillc[c], 1);
    srcs[pos] = (unsigned short)(p >> 16);
  }
}

// zero the 8 sentinel rows of each of the 3 slice tables
__global__ void k_zsent(float* __restrict__ Tall, int N) {
  int t = blockIdx.x * blockDim.x + threadIdx.x;
  if (t < CLS * 8 * 16) {
    int c = t / 128, rem = t % 128;
    int s = rem / 16, f = rem % 16;
    Tall[((size_t)c * 8 + s) * (size_t)(N + 1) * 16 + (size_t)N * 16 + f] = 0.f;
  }
}

// split conv_w into bf16 hi/lo, TRANSPOSED: WhT[cl][col][k]
__global__ void k_wsplit(const float* __restrict__ W, unsigned short* __restrict__ WhT,
                         unsigned short* __restrict__ WlT, int total) {
  int idx = blockIdx.x * blockDim.x + threadIdx.x;
  if (idx >= total) return;
  int cl = idx >> 14;
  int rem = idx & 16383;
  int c = rem >> 7, k = rem & 127;
  float w = W[(size_t)cl * 16384 + k * 128 + c];
  unsigned short h = bf16rne(w);
  WhT[idx] = h;
  WlT[idx] = bf16rne(w - bf16tof(h));
}

// ---- T0 = x * dinv, slice-major [8][N+1][16] ----
__global__ __launch_bounds__(256) void k_scale(const float* __restrict__ x,
                                               const float* __restrict__ dinv,
                                               float* __restrict__ T, int N) {
  const int s = blockIdx.y;
  const int i = blockIdx.x * 64 + (threadIdx.x >> 2);
  const int f = threadIdx.x & 3;
  if (i < N) {
    float4 v = *(const float4*)&x[(size_t)i * 128 + s * 16 + f * 4];
    float d = dinv[i];
    v.x *= d; v.y *= d; v.z *= d; v.w *= d;
    *(float4*)&T[((size_t)s * (N + 1) + i) * 16 + f * 4] = v;
  }
}

// ---- XCD-sliced gather, fused over classes; output split to bf16 hi/lo ----
__global__ __launch_bounds__(256, 4) void k_gather(const float* __restrict__ Tbase, long tstride,
                                                   const int* __restrict__ rptr2,
                                                   const unsigned short* __restrict__ srcs,
                                                   const float* __restrict__ dinv,
                                                   unsigned short* __restrict__ Zh,
                                                   unsigned short* __restrict__ Zl,
                                                   long zstride, int N) {
  const int s = blockIdx.x & 7;
  const int chunk = blockIdx.x >> 3;
  const int i = chunk * 64 + (threadIdx.x >> 2);
  const int f = threadIdx.x & 3;
  if (i >= N) return;
  const float* __restrict__ T = Tbase + (size_t)blockIdx.y * tstride;
  const evf4* __restrict__ Ts = (const evf4*)(T + (size_t)s * (N + 1) * 16);
  const int e0 = rptr2[i], e1 = rptr2[i + 1];
  evf4 a0 = Ts[(size_t)i * 4 + f];  // self term
  evf4 a1 = (evf4)0.f, a2 = (evf4)0.f, a3 = (evf4)0.f;
  uint4 I0 = make_uint4(0, 0, 0, 0), I1 = I0;
  if (e0 < e1) {
    I0 = *(const uint4*)(srcs + e0);
    I1 = *(const uint4*)(srcs + e0 + 8);
  }
  for (int eb = e0; eb < e1; eb += 16) {
    uint4 I0n = I0, I1n = I1;
    if (eb + 16 < e1) {
      I0n = *(const uint4*)(srcs + eb + 16);
      I1n = *(const uint4*)(srcs + eb + 24);
    }
    const int j0  = (int)(I0.x & 0xFFFFu), j1  = (int)(I0.x >> 16);
    const int j2  = (int)(I0.y & 0xFFFFu), j3  = (int)(I0.y >> 16);
    const int j4  = (int)(I0.z & 0xFFFFu), j5  = (int)(I0.z >> 16);
    const int j6  = (int)(I0.w & 0xFFFFu), j7  = (int)(I0.w >> 16);
    const int j8  = (int)(I1.x & 0xFFFFu), j9  = (int)(I1.x >> 16);
    const int j10 = (int)(I1.y & 0xFFFFu), j11 = (int)(I1.y >> 16);
    const int j12 = (int)(I1.z & 0xFFFFu), j13 = (int)(I1.z >> 16);
    const int j14 = (int)(I1.w & 0xFFFFu), j15 = (int)(I1.w >> 16);
    evf4 v0  = Ts[(size_t)j0  * 4 + f];
    evf4 v1  = Ts[(size_t)j1  * 4 + f];
    evf4 v2  = Ts[(size_t)j2  * 4 + f];
    evf4 v3  = Ts[(size_t)j3  * 4 + f];
    evf4 v4  = Ts[(size_t)j4  * 4 + f];
    evf4 v5  = Ts[(size_t)j5  * 4 + f];
    evf4 v6  = Ts[(size_t)j6  * 4 + f];
    evf4 v7  = Ts[(size_t)j7  * 4 + f];
    evf4 v8  = Ts[(size_t)j8  * 4 + f];
    evf4 v9  = Ts[(size_t)j9  * 4 + f];
    evf4 v10 = Ts[(size_t)j10 * 4 + f];
    evf4 v11 = Ts[(size_t)j11 * 4 + f];
    evf4 v12 = Ts[(size_t)j12 * 4 + f];
    evf4 v13 = Ts[(size_t)j13 * 4 + f];
    evf4 v14 = Ts[(size_t)j14 * 4 + f];
    evf4 v15 = Ts[(size_t)j15 * 4 + f];
    asm volatile("" :: "v"(v0), "v"(v1), "v"(v2), "v"(v3),
                       "v"(v4), "v"(v5), "v"(v6), "v"(v7),
                       "v"(v8), "v"(v9), "v"(v10), "v"(v11),
                       "v"(v12), "v"(v13), "v"(v14), "v"(v15));
    __builtin_amdgcn_sched_barrier(0);
    a0 += v0;  a1 += v1;  a2 += v2;  a3 += v3;
    a0 += v4;  a1 += v5;  a2 += v6;  a3 += v7;
    a0 += v8;  a1 += v9;  a2 += v10; a3 += v11;
    a0 += v12; a1 += v13; a2 += v14; a3 += v15;
    I0 = I0n; I1 = I1n;
  }
  const float d = dinv[i];
  evf4 r = (a0 + a1 + a2 + a3) * d;
  ushort4 zh, zl;
  zh.x = bf16rne(r.x); zl.x = bf16rne(r.x - bf16tof(zh.x));
  zh.y = bf16rne(r.y); zl.y = bf16rne(r.y - bf16tof(zh.y));
  zh.z = bf16rne(r.z); zl.z = bf16rne(r.z - bf16tof(zh.z));
  zh.w = bf16rne(r.w); zl.w = bf16rne(r.w - bf16tof(zh.w));
  size_t zo = (size_t)blockIdx.y * zstride + (size_t)i * 128 + s * 16 + f * 4;
  *(ushort4*)&Zh[zo] = zh;
  *(ushort4*)&Zl[zo] = zl;
}

// ---- split-bf16 MFMA GEMM (emulated fp32): C = (Ah+Al)@(Wh+Wl), 4 products ----
// 128x128 block tile, 4 waves (64x64 each), K-step 32, fused bias+L2norm+ReLU.
// MODE 0: Out = slice-major fp32 table (+dinv); MODE 1: row-major fp32 H.
template <int MODE>
__global__ __launch_bounds__(256) void k_gemm3m(
    const unsigned short* __restrict__ Ahb, const unsigned short* __restrict__ Alb,
    long astride,
    const unsigned short* __restrict__ WhT, const unsigned short* __restrict__ WlT,
    int layer, const float* __restrict__ bl, const float* __restrict__ dinv,
    float* __restrict__ Obase, long ostride, int N) {
  __shared__ unsigned short Ash[128 * 40], Asl[128 * 40];
  __shared__ unsigned short Wsh[128 * 40], Wsl[128 * 40];
  __shared__ float red[128][2];

  const int c = blockIdx.y;
  const unsigned short* __restrict__ Ah = Ahb + (size_t)c * astride;
  const unsigned short* __restrict__ Al = Alb + (size_t)c * astride;
  const size_t wslab = (size_t)(c * LAY + layer) * 16384;
  const float* __restrict__ bias = bl + (size_t)(c * LAY + layer) * D;
  float* __restrict__ Out = Obase + (size_t)c * ostride;

  const int tid = threadIdx.x;
  const int w = tid >> 6, l = tid & 63;
  const int wr = w >> 1, wc = w & 1;
  const int lg = l >> 4, li = l & 15;
  const int m0 = blockIdx.x * 128;

  f32x4 acc[4][4];
#pragma unroll
  for (int i = 0; i < 4; ++i)
#pragma unroll
    for (int j = 0; j < 4; ++j) acc[i][j] = (f32x4)0.f;

  const int srow = tid >> 1;
  const int sk = (tid & 1) * 8;
  const bool rowok = (m0 + srow) < N;

  for (int kc = 0; kc < 128; kc += 32) {
    uint4 z4 = make_uint4(0, 0, 0, 0);
    uint4 ah0 = z4, ah1 = z4, al0 = z4, al1 = z4;
    if (rowok) {
      const size_t ab = (size_t)(m0 + srow) * 128 + kc + sk;
      ah0 = *(const uint4*)&Ah[ab];
      ah1 = *(const uint4*)&Ah[ab + 16];
      al0 = *(const uint4*)&Al[ab];
      al1 = *(const uint4*)&Al[ab + 16];
    }
    const size_t wb = wslab + (size_t)srow * 128 + kc + sk;
    uint4 wh0 = *(const uint4*)&WhT[wb];
    uint4 wh1 = *(const uint4*)&WhT[wb + 16];
    uint4 wl0 = *(const uint4*)&WlT[wb];
    uint4 wl1 = *(const uint4*)&WlT[wb + 16];
    if (kc) __syncthreads();
    *(uint4*)&Ash[srow * 40 + sk] = ah0;
    *(uint4*)&Ash[srow * 40 + sk + 16] = ah1;
    *(uint4*)&Asl[srow * 40 + sk] = al0;
    *(uint4*)&Asl[srow * 40 + sk + 16] = al1;
    *(uint4*)&Wsh[srow * 40 + sk] = wh0;
    *(uint4*)&Wsh[srow * 40 + sk + 16] = wh1;
    *(uint4*)&Wsl[srow * 40 + sk] = wl0;
    *(uint4*)&Wsl[srow * 40 + sk + 16] = wl1;
    __syncthreads();

    bf16x8 fah[4], fal[4];
#pragma unroll
    for (int rf = 0; rf < 4; ++rf) {
      const int arow = wr * 64 + rf * 16 + li;
      fah[rf] = *(const bf16x8*)&Ash[arow * 40 + lg * 8];
      fal[rf] = *(const bf16x8*)&Asl[arow * 40 + lg * 8];
    }
#pragma unroll
    for (int cf = 0; cf < 4; ++cf) {
      const int bcol = wc * 64 + cf * 16 + li;
      bf16x8 fbh = *(const bf16x8*)&Wsh[bcol * 40 + lg * 8];
      bf16x8 fbl = *(const bf16x8*)&Wsl[bcol * 40 + lg * 8];
#pragma unroll
      for (int rf = 0; rf < 4; ++rf) {
        acc[rf][cf] = __builtin_amdgcn_mfma_f32_16x16x32_bf16(fah[rf], fbh, acc[rf][cf], 0, 0, 0);
        acc[rf][cf] = __builtin_amdgcn_mfma_f32_16x16x32_bf16(fah[rf], fbl, acc[rf][cf], 0, 0, 0);
        acc[rf][cf] = __builtin_amdgcn_mfma_f32_16x16x32_bf16(fal[rf], fbh, acc[rf][cf], 0, 0, 0);
        acc[rf][cf] = __builtin_amdgcn_mfma_f32_16x16x32_bf16(fal[rf], fbl, acc[rf][cf], 0, 0, 0);
      }
    }
  }
  __syncthreads();

  // epilogue: bias, row L2-norm (cross-lane + cross-wave), relu, (dinv), store
  float bj[4];
#pragma unroll
  for (int cf = 0; cf < 4; ++cf) bj[cf] = bias[wc * 64 + cf * 16 + li];
#pragma unroll
  for (int rf = 0; rf < 4; ++rf) {
#pragma unroll
    for (int r = 0; r < 4; ++r) {
      float sq = 0.f;
#pragma unroll
      for (int cf = 0; cf < 4; ++cf) {
        float v = acc[rf][cf][r] + bj[cf];
        acc[rf][cf][r] = v;
        sq = fmaf(v, v, sq);
      }
#pragma unroll
      for (int m = 1; m < 16; m <<= 1) sq += __shfl_xor(sq, m, 16);
      if (li == 0) red[wr * 64 + rf * 16 + lg * 4 + r][wc] = sq;
    }
  }
  __syncthreads();
#pragma unroll
  for (int rf = 0; rf < 4; ++rf) {
#pragma unroll
    for (int r = 0; r < 4; ++r) {
      const int rrow = wr * 64 + rf * 16 + lg * 4 + r;
      const int grow = m0 + rrow;
      if (grow >= N) continue;
      float rsum = red[rrow][0] + red[rrow][1];
      float sc = 1.0f / fmaxf(sqrtf(rsum), 1e-12f);
      if (MODE == 0) sc *= dinv[grow];
#pragma unroll
      for (int cf = 0; cf < 4; ++cf) {
        float v = fmaxf(acc[rf][cf][r] * sc, 0.f);
        if (MODE == 0) {
          const int sidx = wc * 4 + cf;
          Out[((size_t)sidx * (N + 1) + grow) * 16 + li] = v;
        } else {
          Out[(size_t)grow * 128 + wc * 64 + cf * 16 + li] = v;
        }
      }
    }
  }
}

// ------------- batched head: pool + lin1 + ReLU + lin2 (blockIdx.y = class) -------------
__device__ __forceinline__ int lowerb(const int* __restrict__ a, int n, int v) {
  int lo = 0, hi = n;
  while (lo < hi) {
    int m = (lo + hi) >> 1;
    if (a[m] < v) lo = m + 1; else hi = m;
  }
  return lo;
}

__global__ __launch_bounds__(128) void k_head(const float* __restrict__ Hall, long hstride,
                                              const int* __restrict__ batch, int N,
                                              const float* __restrict__ l1w,
                                              const float* __restrict__ l1b,
                                              const float* __restrict__ l2w,
                                              const float* __restrict__ l2b,
                                              float* __restrict__ out, int G) {
  const int g = blockIdx.x;
  const int c = blockIdx.y;
  const int t = threadIdx.x;
  const float* __restrict__ h = Hall + (size_t)c * hstride;
  const float* __restrict__ w1 = l1w + (size_t)c * D * D;
  const float* __restrict__ w2 = l2w + (size_t)c * D;
  int lo = lowerb(batch, N, g);
  int hi = lowerb(batch, N, g + 1);
  float p = 0.f;
  for (int i = lo; i < hi; ++i) p += h[(size_t)i * 128 + t];
  __shared__ float pl[128];
  pl[t] = p;
  __syncthreads();
  float z = l1b[(size_t)c * D + t];
#pragma unroll 8
  for (int k = 0; k < 128; ++k) z = fmaf(pl[k], w1[k * 128 + t], z);
  z = fmaxf(z, 0.f);
  float o = z * w2[t];
#pragma unroll
  for (int off = 32; off > 0; off >>= 1) o += __shfl_xor(o, off, 64);
  __shared__ float s2[2];
  if ((t & 63) == 0) s2[t >> 6] = o;
  __syncthreads();
  if (t == 0) out[(size_t)g * CLS + c] = s2[0] + s2[1] + l2b[c];
}

extern "C" void kernel_launch(void* const* d_in, const int* in_sizes, int n_in,
                              void* d_out, int out_size, void* d_ws, size_t ws_size,
                              hipStream_t stream) {
  const float* x = (const float*)d_in[0];
  const int* eidx = (const int*)d_in[1];
  const int* batch = (const int*)d_in[2];
  const float* conv_w = (const float*)d_in[3];
  const float* conv_b = (const float*)d_in[4];
  const float* lin1_w = (const float*)d_in[5];
  const float* lin1_b = (const float*)d_in[6];
  const float* lin2_w = (const float*)d_in[7];
  const float* lin2_b = (const float*)d_in[8];
  float* out = (float*)d_out;

  const int N = in_sizes[0] / D;
  const int E = in_sizes[1] / 2;
  const int G = out_size / CLS;
  const int* row = eidx;
  const int* col = eidx + E;

  int bshift = 10;
  while ((1 << bshift) < E / NBKT + 32768) ++bshift;
  const long TS = (long)(N + 1) * 128;   // per-class slice-table stride (floats)
  const long ZS2 = (long)N * 128;        // per-class bf16 stride (ushort elems)

  char* ws = (char*)d_ws;
  size_t off = 0;
  auto alloc = [&](size_t bytes) -> void* {
    void* p = ws + off;
    off += (bytes + 255) & ~(size_t)255;
    return p;
  };
  unsigned short* Zh = (unsigned short*)alloc((size_t)CLS * ZS2 * 2);
  unsigned short* Zl = (unsigned short*)alloc((size_t)CLS * ZS2 * 2);
  float* Tall = (float*)alloc((size_t)CLS * TS * 4);
  unsigned short* WhT = (unsigned short*)alloc((size_t)CLS * LAY * D * D * 2);
  unsigned short* WlT = (unsigned short*)alloc((size_t)CLS * LAY * D * D * 2);
  unsigned short* srcs = (unsigned short*)alloc(((size_t)E + 16 * (size_t)N + 64) * 2);
  int* cnt    = (int*)alloc(((size_t)N * 2 + NBKT) * 4);
  int* fillc  = cnt + N;
  int* bfill  = cnt + 2 * N;
  int* rptr2  = (int*)alloc((size_t)(N + 1) * 4);
  float* dinv = (float*)alloc((size_t)N * 4);
  unsigned* pairs = (unsigned*)Tall;  // alias: dead before k_zsent/k_scale
  (void)ws_size; (void)n_in;

  hipMemsetAsync(cnt, 0, ((size_t)N * 2 + NBKT) * 4, stream);
  const int nb = (N + 255) / 256;
  const int wtot = CLS * LAY * D * D;
  k_bin<<<1024, 256, 0, stream>>>(row, col, cnt, bfill, pairs, E, (float)NBKT / (float)N, bshift);
  k_exscan<<<1, 1024, 0, stream>>>(cnt, rptr2, N);
  k_prep<<<nb, 256, 0, stream>>>(cnt, rptr2, dinv, srcs, N);
  k_fill2<<<1024, 256, 0, stream>>>(pairs, bfill, rptr2, fillc, srcs, bshift);
  k_zsent<<<2, 256, 0, stream>>>(Tall, N);
  k_wsplit<<<(wtot + 255) / 256, 256, 0, stream>>>(conv_w, WhT, WlT, wtot);

  const int NB64 = (N + 63) / 64;
  const int gb = (N + 127) / 128;

  // shared layer 0
  k_scale<<<dim3(NB64, 8), 256, 0, stream>>>(x, dinv, Tall, N);
  k_gather<<<dim3(NB64 * 8, 1), 256, 0, stream>>>(Tall, 0L, rptr2, srcs, dinv, Zh, Zl, 0L, N);

  // layer 1 (A shared across classes)
  k_gemm3m<0><<<dim3(gb, CLS), 256, 0, stream>>>(Zh, Zl, 0L, WhT, WlT, 0,
                                                 conv_b, dinv, Tall, TS, N);
  k_gather<<<dim3(NB64 * 8, CLS), 256, 0, stream>>>(Tall, TS, rptr2, srcs, dinv, Zh, Zl, ZS2, N);

  // layer 2
  k_gemm3m<0><<<dim3(gb, CLS), 256, 0, stream>>>(Zh, Zl, ZS2, WhT, WlT, 1,
                                                 conv_b, dinv, Tall, TS, N);
  k_gather<<<dim3(NB64 * 8, CLS), 256, 0, stream>>>(Tall, TS, rptr2, srcs, dinv, Zh, Zl, ZS2, N);

  // layer 3 -> H (row-major fp32, stored in the table slots)
  k_gemm3m<1><<<dim3(gb, CLS), 256, 0, stream>>>(Zh, Zl, ZS2, WhT, WlT, 2,
                                                 conv_b, dinv, Tall, TS, N);

  // heads
  k_head<<<dim3(G, CLS), 128, 0, stream>>>(Tall, TS, batch, N,
                                           lin1_w, lin1_b, lin2_w, lin2_b, out, G);
}

// Round 15
// 807.468 us; speedup vs baseline: 3.8283x; 1.0851x over previous
//
#include <hip/hip_runtime.h>

#define D 128
#define CLS 3
#define LAY 3
#define NBKT 8

typedef __attribute__((ext_vector_type(4))) float evf4;
typedef __attribute__((ext_vector_type(8))) short bf16x8;
typedef __attribute__((ext_vector_type(4))) float f32x4;

__device__ __forceinline__ unsigned short bf16rne(float x) {
  unsigned b = __float_as_uint(x);
  unsigned r = b + 0x7FFFu + ((b >> 16) & 1u);
  return (unsigned short)(r >> 16);
}
__device__ __forceinline__ float bf16tof(unsigned short h) {
  return __uint_as_float(((unsigned)h) << 16);
}

// exclusive scan of PADDED counts: pad(cnt) = (cnt+15)&~15  -> rptr2
__global__ __launch_bounds__(1024) void k_exscan(const int* __restrict__ cnt,
                                                 int* __restrict__ ptr, int n) {
  __shared__ int wsum[16];
  __shared__ int s_carry;
  const int tid = threadIdx.x;
  const int lane = tid & 63, wid = tid >> 6;
  if (tid == 0) s_carry = 0;
  __syncthreads();
  for (int base = 0; base < n; base += 1024) {
    int i = base + tid;
    int v = (i < n) ? ((cnt[i] + 15) & ~15) : 0;
    int s = v;
#pragma unroll
    for (int off = 1; off < 64; off <<= 1) {
      int t = __shfl_up(s, off, 64);
      if (lane >= off) s += t;
    }
    if (lane == 63) wsum[wid] = s;
    __syncthreads();
    if (wid == 0 && lane < 16) {
      int ws = wsum[lane];
#pragma unroll
      for (int off = 1; off < 16; off <<= 1) {
        int t = __shfl_up(ws, off, 16);
        if (lane >= off) ws += t;
      }
      wsum[lane] = ws;
    }
    __syncthreads();
    int carry = s_carry;
    int woff = wid ? wsum[wid - 1] : 0;
    if (i < n) ptr[i] = carry + woff + (s - v);
    __syncthreads();
    if (tid == 1023) s_carry = carry + wsum[15];
    __syncthreads();
  }
  if (tid == 0) ptr[n] = s_carry;
}

// dinv + fill CSR padding slots with sentinel N
__global__ void k_prep(const int* __restrict__ cnt, const int* __restrict__ rptr2,
                       float* __restrict__ dinv, unsigned short* __restrict__ srcs, int N) {
  int i = blockIdx.x * blockDim.x + threadIdx.x;
  if (i < N) {
    dinv[i] = rsqrtf((float)(cnt[i] + 1));
    int e = rptr2[i] + cnt[i], e1 = rptr2[i + 1];
    for (; e < e1; ++e) srcs[e] = (unsigned short)N;  // sentinel -> zero row
  }
}

// phase A: per-node degree count + bin edges into 8 col-range buckets
__global__ __launch_bounds__(256) void k_bin(const int* __restrict__ row,
                                             const int* __restrict__ col,
                                             int* __restrict__ cnt,
                                             int* __restrict__ bfill,
                                             unsigned* __restrict__ pairs,
                                             int E, float bscale, int bshift) {
  __shared__ int lh[NBKT], gbase[NBKT], lcur[NBKT];
  const int tid = threadIdx.x;
  const int chunk = (E + gridDim.x - 1) / gridDim.x;
  const int s0 = blockIdx.x * chunk;
  const int s1 = min(s0 + chunk, E);
  if (tid < NBKT) lh[tid] = 0;
  __syncthreads();
  for (int e = s0 + tid; e < s1; e += 256) {
    int c = col[e];
    atomicAdd(&cnt[c], 1);
    int b = min(NBKT - 1, (int)((float)c * bscale));
    atomicAdd(&lh[b], 1);
  }
  __syncthreads();
  if (tid < NBKT) {
    gbase[tid] = atomicAdd(&bfill[tid], lh[tid]);
    lcur[tid] = 0;
  }
  __syncthreads();
  for (int e = s0 + tid; e < s1; e += 256) {
    int c = col[e], r = row[e];
    int b = min(NBKT - 1, (int)((float)c * bscale));
    int off = atomicAdd(&lcur[b], 1);
    pairs[(b << bshift) + gbase[b] + off] = ((unsigned)r << 16) | (unsigned)c;
  }
}

// phase B: XCD-affine scatter into padded CSR (bucket b on blocks with blockIdx&7==b)
__global__ __launch_bounds__(256) void k_fill2(const unsigned* __restrict__ pairs,
                                               const int* __restrict__ bfill,
                                               const int* __restrict__ rptr2,
                                               int* __restrict__ fillc,
                                               unsigned short* __restrict__ srcs,
                                               int bshift) {
  const int b = blockIdx.x & 7;
  const int bi = blockIdx.x >> 3;
  const int cap = bfill[b];
  const int stride = (gridDim.x >> 3) * blockDim.x;
  const unsigned* __restrict__ bp = pairs + ((size_t)b << bshift);
  for (int idx = bi * blockDim.x + threadIdx.x; idx < cap; idx += stride) {
    unsigned p = bp[idx];
    int c = (int)(p & 0xFFFFu);
    int pos = rptr2[c] + atomicAdd(&fillc[c], 1);
    srcs[pos] = (unsigned short)(p >> 16);
  }
}

// zero the 8 sentinel rows of each of the 3 slice tables
__global__ void k_zsent(float* __restrict__ Tall, int N) {
  int t = blockIdx.x * blockDim.x + threadIdx.x;
  if (t < CLS * 8 * 16) {
    int c = t / 128, rem = t % 128;
    int s = rem / 16, f = rem % 16;
    Tall[((size_t)c * 8 + s) * (size_t)(N + 1) * 16 + (size_t)N * 16 + f] = 0.f;
  }
}

// split conv_w into bf16 hi/lo, TRANSPOSED: WhT[cl][col][k]
__global__ void k_wsplit(const float* __restrict__ W, unsigned short* __restrict__ WhT,
                         unsigned short* __restrict__ WlT, int total) {
  int idx = blockIdx.x * blockDim.x + threadIdx.x;
  if (idx >= total) return;
  int cl = idx >> 14;
  int rem = idx & 16383;
  int c = rem >> 7, k = rem & 127;
  float w = W[(size_t)cl * 16384 + k * 128 + c];
  unsigned short h = bf16rne(w);
  WhT[idx] = h;
  WlT[idx] = bf16rne(w - bf16tof(h));
}

// ---- T0 = x * dinv, slice-major [8][N+1][16] ----
__global__ __launch_bounds__(256) void k_scale(const float* __restrict__ x,
                                               const float* __restrict__ dinv,
                                               float* __restrict__ T, int N) {
  const int s = blockIdx.y;
  const int i = blockIdx.x * 64 + (threadIdx.x >> 2);
  const int f = threadIdx.x & 3;
  if (i < N) {
    float4 v = *(const float4*)&x[(size_t)i * 128 + s * 16 + f * 4];
    float d = dinv[i];
    v.x *= d; v.y *= d; v.z *= d; v.w *= d;
    *(float4*)&T[((size_t)s * (N + 1) + i) * 16 + f * 4] = v;
  }
}

// ---- XCD-sliced gather, fused over classes (blockIdx.y = class); fp32 full-line out ----
__global__ __launch_bounds__(256, 4) void k_gather(const float* __restrict__ Tbase, long tstride,
                                                   const int* __restrict__ rptr2,
                                                   const unsigned short* __restrict__ srcs,
                                                   const float* __restrict__ dinv,
                                                   float* __restrict__ Zbase, long zstride,
                                                   int N) {
  const int s = blockIdx.x & 7;
  const int chunk = blockIdx.x >> 3;
  const int i = chunk * 64 + (threadIdx.x >> 2);
  const int f = threadIdx.x & 3;
  if (i >= N) return;
  const float* __restrict__ T = Tbase + (size_t)blockIdx.y * tstride;
  float* __restrict__ Z = Zbase + (size_t)blockIdx.y * zstride;
  const evf4* __restrict__ Ts = (const evf4*)(T + (size_t)s * (N + 1) * 16);
  const int e0 = rptr2[i], e1 = rptr2[i + 1];
  evf4 a0 = Ts[(size_t)i * 4 + f];  // self term
  evf4 a1 = (evf4)0.f, a2 = (evf4)0.f, a3 = (evf4)0.f;
  uint4 I0 = make_uint4(0, 0, 0, 0), I1 = I0;
  if (e0 < e1) {
    I0 = *(const uint4*)(srcs + e0);
    I1 = *(const uint4*)(srcs + e0 + 8);
  }
  for (int eb = e0; eb < e1; eb += 16) {
    uint4 I0n = I0, I1n = I1;
    if (eb + 16 < e1) {
      I0n = *(const uint4*)(srcs + eb + 16);
      I1n = *(const uint4*)(srcs + eb + 24);
    }
    const int j0  = (int)(I0.x & 0xFFFFu), j1  = (int)(I0.x >> 16);
    const int j2  = (int)(I0.y & 0xFFFFu), j3  = (int)(I0.y >> 16);
    const int j4  = (int)(I0.z & 0xFFFFu), j5  = (int)(I0.z >> 16);
    const int j6  = (int)(I0.w & 0xFFFFu), j7  = (int)(I0.w >> 16);
    const int j8  = (int)(I1.x & 0xFFFFu), j9  = (int)(I1.x >> 16);
    const int j10 = (int)(I1.y & 0xFFFFu), j11 = (int)(I1.y >> 16);
    const int j12 = (int)(I1.z & 0xFFFFu), j13 = (int)(I1.z >> 16);
    const int j14 = (int)(I1.w & 0xFFFFu), j15 = (int)(I1.w >> 16);
    evf4 v0  = Ts[(size_t)j0  * 4 + f];
    evf4 v1  = Ts[(size_t)j1  * 4 + f];
    evf4 v2  = Ts[(size_t)j2  * 4 + f];
    evf4 v3  = Ts[(size_t)j3  * 4 + f];
    evf4 v4  = Ts[(size_t)j4  * 4 + f];
    evf4 v5  = Ts[(size_t)j5  * 4 + f];
    evf4 v6  = Ts[(size_t)j6  * 4 + f];
    evf4 v7  = Ts[(size_t)j7  * 4 + f];
    evf4 v8  = Ts[(size_t)j8  * 4 + f];
    evf4 v9  = Ts[(size_t)j9  * 4 + f];
    evf4 v10 = Ts[(size_t)j10 * 4 + f];
    evf4 v11 = Ts[(size_t)j11 * 4 + f];
    evf4 v12 = Ts[(size_t)j12 * 4 + f];
    evf4 v13 = Ts[(size_t)j13 * 4 + f];
    evf4 v14 = Ts[(size_t)j14 * 4 + f];
    evf4 v15 = Ts[(size_t)j15 * 4 + f];
    asm volatile("" :: "v"(v0), "v"(v1), "v"(v2), "v"(v3),
                       "v"(v4), "v"(v5), "v"(v6), "v"(v7),
                       "v"(v8), "v"(v9), "v"(v10), "v"(v11),
                       "v"(v12), "v"(v13), "v"(v14), "v"(v15));
    __builtin_amdgcn_sched_barrier(0);
    a0 += v0;  a1 += v1;  a2 += v2;  a3 += v3;
    a0 += v4;  a1 += v5;  a2 += v6;  a3 += v7;
    a0 += v8;  a1 += v9;  a2 += v10; a3 += v11;
    a0 += v12; a1 += v13; a2 += v14; a3 += v15;
    I0 = I0n; I1 = I1n;
  }
  const float d = dinv[i];
  evf4 r = (a0 + a1 + a2 + a3) * d;
  *(evf4*)&Z[(size_t)i * 128 + s * 16 + f * 4] = r;
}

// ---- split-bf16 MFMA GEMM (emulated fp32), A split in-kernel from fp32 ----
// C = Ah@Wh + Ah@Wl + Al@Wh (Al@Wl dropped: ~2^-18 rel). 128x128 tile, 4 waves,
// K-step 32. MODE 0: slice-major fp32 table (+dinv); MODE 1: row-major fp32 H.
template <int MODE>
__global__ __launch_bounds__(256) void k_gemm3m(
    const float* __restrict__ Abase, long astride,
    const unsigned short* __restrict__ WhT, const unsigned short* __restrict__ WlT,
    int layer, const float* __restrict__ bl, const float* __restrict__ dinv,
    float* __restrict__ Obase, long ostride, int N) {
  __shared__ unsigned short Ash[128 * 40], Asl[128 * 40];
  __shared__ unsigned short Wsh[128 * 40], Wsl[128 * 40];
  __shared__ float red[128][2];

  const int c = blockIdx.y;
  const float* __restrict__ A = Abase + (size_t)c * astride;
  const size_t wslab = (size_t)(c * LAY + layer) * 16384;
  const float* __restrict__ bias = bl + (size_t)(c * LAY + layer) * D;
  float* __restrict__ Out = Obase + (size_t)c * ostride;

  const int tid = threadIdx.x;
  const int w = tid >> 6, l = tid & 63;
  const int wr = w >> 1, wc = w & 1;
  const int lg = l >> 4, li = l & 15;
  const int m0 = blockIdx.x * 128;

  f32x4 acc[4][4];
#pragma unroll
  for (int i = 0; i < 4; ++i)
#pragma unroll
    for (int j = 0; j < 4; ++j) acc[i][j] = (f32x4)0.f;

  const int srow = tid >> 1;
  const int half = tid & 1;        // which 16-k half of the 32-k tile
  const bool rowok = (m0 + srow) < N;

  for (int kc = 0; kc < 128; kc += 32) {
    float fa[16];
#pragma unroll
    for (int j = 0; j < 16; ++j) fa[j] = 0.f;
    if (rowok) {
      const size_t ab = (size_t)(m0 + srow) * 128 + kc + half * 16;
      *(float4*)&fa[0]  = *(const float4*)&A[ab];
      *(float4*)&fa[4]  = *(const float4*)&A[ab + 4];
      *(float4*)&fa[8]  = *(const float4*)&A[ab + 8];
      *(float4*)&fa[12] = *(const float4*)&A[ab + 12];
    }
    const size_t wb = wslab + (size_t)srow * 128 + kc + half * 16;
    uint4 wh0 = *(const uint4*)&WhT[wb];
    uint4 wh1 = *(const uint4*)&WhT[wb + 8];
    uint4 wl0 = *(const uint4*)&WlT[wb];
    uint4 wl1 = *(const uint4*)&WlT[wb + 8];

    unsigned hpk[8], lpk[8];
#pragma unroll
    for (int j = 0; j < 8; ++j) {
      unsigned short h0 = bf16rne(fa[2 * j]);
      unsigned short h1 = bf16rne(fa[2 * j + 1]);
      float l0 = fa[2 * j] - bf16tof(h0);
      float l1 = fa[2 * j + 1] - bf16tof(h1);
      hpk[j] = (unsigned)h0 | ((unsigned)h1 << 16);
      lpk[j] = (unsigned)bf16rne(l0) | ((unsigned)bf16rne(l1) << 16);
    }
    if (kc) __syncthreads();
    *(uint4*)&Ash[srow * 40 + half * 16]     = make_uint4(hpk[0], hpk[1], hpk[2], hpk[3]);
    *(uint4*)&Ash[srow * 40 + half * 16 + 8] = make_uint4(hpk[4], hpk[5], hpk[6], hpk[7]);
    *(uint4*)&Asl[srow * 40 + half * 16]     = make_uint4(lpk[0], lpk[1], lpk[2], lpk[3]);
    *(uint4*)&Asl[srow * 40 + half * 16 + 8] = make_uint4(lpk[4], lpk[5], lpk[6], lpk[7]);
    *(uint4*)&Wsh[srow * 40 + half * 16]     = wh0;
    *(uint4*)&Wsh[srow * 40 + half * 16 + 8] = wh1;
    *(uint4*)&Wsl[srow * 40 + half * 16]     = wl0;
    *(uint4*)&Wsl[srow * 40 + half * 16 + 8] = wl1;
    __syncthreads();

    bf16x8 fah[4], fal[4];
#pragma unroll
    for (int rf = 0; rf < 4; ++rf) {
      const int arow = wr * 64 + rf * 16 + li;
      fah[rf] = *(const bf16x8*)&Ash[arow * 40 + lg * 8];
      fal[rf] = *(const bf16x8*)&Asl[arow * 40 + lg * 8];
    }
#pragma unroll
    for (int cf = 0; cf < 4; ++cf) {
      const int bcol = wc * 64 + cf * 16 + li;
      bf16x8 fbh = *(const bf16x8*)&Wsh[bcol * 40 + lg * 8];
      bf16x8 fbl = *(const bf16x8*)&Wsl[bcol * 40 + lg * 8];
#pragma unroll
      for (int rf = 0; rf < 4; ++rf) {
        acc[rf][cf] = __builtin_amdgcn_mfma_f32_16x16x32_bf16(fah[rf], fbh, acc[rf][cf], 0, 0, 0);
        acc[rf][cf] = __builtin_amdgcn_mfma_f32_16x16x32_bf16(fah[rf], fbl, acc[rf][cf], 0, 0, 0);
        acc[rf][cf] = __builtin_amdgcn_mfma_f32_16x16x32_bf16(fal[rf], fbh, acc[rf][cf], 0, 0, 0);
      }
    }
  }
  __syncthreads();

  // epilogue: bias, row L2-norm (cross-lane + cross-wave), relu, (dinv), store
  float bj[4];
#pragma unroll
  for (int cf = 0; cf < 4; ++cf) bj[cf] = bias[wc * 64 + cf * 16 + li];
#pragma unroll
  for (int rf = 0; rf < 4; ++rf) {
#pragma unroll
    for (int r = 0; r < 4; ++r) {
      float sq = 0.f;
#pragma unroll
      for (int cf = 0; cf < 4; ++cf) {
        float v = acc[rf][cf][r] + bj[cf];
        acc[rf][cf][r] = v;
        sq = fmaf(v, v, sq);
      }
#pragma unroll
      for (int m = 1; m < 16; m <<= 1) sq += __shfl_xor(sq, m, 16);
      if (li == 0) red[wr * 64 + rf * 16 + lg * 4 + r][wc] = sq;
    }
  }
  __syncthreads();
#pragma unroll
  for (int rf = 0; rf < 4; ++rf) {
#pragma unroll
    for (int r = 0; r < 4; ++r) {
      const int rrow = wr * 64 + rf * 16 + lg * 4 + r;
      const int grow = m0 + rrow;
      if (grow >= N) continue;
      float rsum = red[rrow][0] + red[rrow][1];
      float sc = 1.0f / fmaxf(sqrtf(rsum), 1e-12f);
      if (MODE == 0) sc *= dinv[grow];
#pragma unroll
      for (int cf = 0; cf < 4; ++cf) {
        float v = fmaxf(acc[rf][cf][r] * sc, 0.f);
        if (MODE == 0) {
          const int sidx = wc * 4 + cf;
          Out[((size_t)sidx * (N + 1) + grow) * 16 + li] = v;
        } else {
          Out[(size_t)grow * 128 + wc * 64 + cf * 16 + li] = v;
        }
      }
    }
  }
}

// ------------- batched head: pool + lin1 + ReLU + lin2 (blockIdx.y = class) -------------
__device__ __forceinline__ int lowerb(const int* __restrict__ a, int n, int v) {
  int lo = 0, hi = n;
  while (lo < hi) {
    int m = (lo + hi) >> 1;
    if (a[m] < v) lo = m + 1; else hi = m;
  }
  return lo;
}

__global__ __launch_bounds__(128) void k_head(const float* __restrict__ Hall, long hstride,
                                              const int* __restrict__ batch, int N,
                                              const float* __restrict__ l1w,
                                              const float* __restrict__ l1b,
                                              const float* __restrict__ l2w,
                                              const float* __restrict__ l2b,
                                              float* __restrict__ out, int G) {
  const int g = blockIdx.x;
  const int c = blockIdx.y;
  const int t = threadIdx.x;
  const float* __restrict__ h = Hall + (size_t)c * hstride;
  const float* __restrict__ w1 = l1w + (size_t)c * D * D;
  const float* __restrict__ w2 = l2w + (size_t)c * D;
  int lo = lowerb(batch, N, g);
  int hi = lowerb(batch, N, g + 1);
  float p = 0.f;
  for (int i = lo; i < hi; ++i) p += h[(size_t)i * 128 + t];
  __shared__ float pl[128];
  pl[t] = p;
  __syncthreads();
  float z = l1b[(size_t)c * D + t];
#pragma unroll 8
  for (int k = 0; k < 128; ++k) z = fmaf(pl[k], w1[k * 128 + t], z);
  z = fmaxf(z, 0.f);
  float o = z * w2[t];
#pragma unroll
  for (int off = 32; off > 0; off >>= 1) o += __shfl_xor(o, off, 64);
  __shared__ float s2[2];
  if ((t & 63) == 0) s2[t >> 6] = o;
  __syncthreads();
  if (t == 0) out[(size_t)g * CLS + c] = s2[0] + s2[1] + l2b[c];
}

extern "C" void kernel_launch(void* const* d_in, const int* in_sizes, int n_in,
                              void* d_out, int out_size, void* d_ws, size_t ws_size,
                              hipStream_t stream) {
  const float* x = (const float*)d_in[0];
  const int* eidx = (const int*)d_in[1];
  const int* batch = (const int*)d_in[2];
  const float* conv_w = (const float*)d_in[3];
  const float* conv_b = (const float*)d_in[4];
  const float* lin1_w = (const float*)d_in[5];
  const float* lin1_b = (const float*)d_in[6];
  const float* lin2_w = (const float*)d_in[7];
  const float* lin2_b = (const float*)d_in[8];
  float* out = (float*)d_out;

  const int N = in_sizes[0] / D;
  const int E = in_sizes[1] / 2;
  const int G = out_size / CLS;
  const int* row = eidx;
  const int* col = eidx + E;

  int bshift = 10;
  while ((1 << bshift) < E / NBKT + 32768) ++bshift;
  const long TS = (long)(N + 1) * 128;  // per-class slice-table stride (floats)
  const long ZS = (long)N * 128;        // per-class row-major stride (floats)

  char* ws = (char*)d_ws;
  size_t off = 0;
  auto alloc = [&](size_t bytes) -> void* {
    void* p = ws + off;
    off += (bytes + 255) & ~(size_t)255;
    return p;
  };
  float* Zall = (float*)alloc((size_t)CLS * ZS * 4);
  float* Tall = (float*)alloc((size_t)CLS * TS * 4);
  unsigned short* WhT = (unsigned short*)alloc((size_t)CLS * LAY * D * D * 2);
  unsigned short* WlT = (unsigned short*)alloc((size_t)CLS * LAY * D * D * 2);
  unsigned short* srcs = (unsigned short*)alloc(((size_t)E + 16 * (size_t)N + 64) * 2);
  int* cnt    = (int*)alloc(((size_t)N * 2 + NBKT) * 4);
  int* fillc  = cnt + N;
  int* bfill  = cnt + 2 * N;
  int* rptr2  = (int*)alloc((size_t)(N + 1) * 4);
  float* dinv = (float*)alloc((size_t)N * 4);
  unsigned* pairs = (unsigned*)Tall;  // alias: dead before k_zsent/k_scale
  (void)ws_size; (void)n_in;

  hipMemsetAsync(cnt, 0, ((size_t)N * 2 + NBKT) * 4, stream);
  const int nb = (N + 255) / 256;
  const int wtot = CLS * LAY * D * D;
  k_bin<<<1024, 256, 0, stream>>>(row, col, cnt, bfill, pairs, E, (float)NBKT / (float)N, bshift);
  k_exscan<<<1, 1024, 0, stream>>>(cnt, rptr2, N);
  k_prep<<<nb, 256, 0, stream>>>(cnt, rptr2, dinv, srcs, N);
  k_fill2<<<1024, 256, 0, stream>>>(pairs, bfill, rptr2, fillc, srcs, bshift);
  k_zsent<<<2, 256, 0, stream>>>(Tall, N);
  k_wsplit<<<(wtot + 255) / 256, 256, 0, stream>>>(conv_w, WhT, WlT, wtot);

  const int NB64 = (N + 63) / 64;
  const int gb = (N + 127) / 128;
  float* Z0 = Zall;

  // shared layer 0
  k_scale<<<dim3(NB64, 8), 256, 0, stream>>>(x, dinv, Tall, N);
  k_gather<<<dim3(NB64 * 8, 1), 256, 0, stream>>>(Tall, 0L, rptr2, srcs, dinv, Z0, 0L, N);

  // layer 1 (A shared across classes)
  k_gemm3m<0><<<dim3(gb, CLS), 256, 0, stream>>>(Z0, 0L, WhT, WlT, 0,
                                                 conv_b, dinv, Tall, TS, N);
  k_gather<<<dim3(NB64 * 8, CLS), 256, 0, stream>>>(Tall, TS, rptr2, srcs, dinv, Zall, ZS, N);

  // layer 2
  k_gemm3m<0><<<dim3(gb, CLS), 256, 0, stream>>>(Zall, ZS, WhT, WlT, 1,
                                                 conv_b, dinv, Tall, TS, N);
  k_gather<<<dim3(NB64 * 8, CLS), 256, 0, stream>>>(Tall, TS, rptr2, srcs, dinv, Zall, ZS, N);

  // layer 3 -> H (row-major fp32, stored in the table slots)
  k_gemm3m<1><<<dim3(gb, CLS), 256, 0, stream>>>(Zall, ZS, WhT, WlT, 2,
                                                 conv_b, dinv, Tall, TS, N);

  // heads
  k_head<<<dim3(G, CLS), 128, 0, stream>>>(Tall, TS, batch, N,
                                           lin1_w, lin1_b, lin2_w, lin2_b, out, G);
}

// Round 16
// 764.786 us; speedup vs baseline: 4.0419x; 1.0558x over previous
//
#include <hip/hip_runtime.h>

#define D 128
#define CLS 3
#define LAY 3
#define NBKT 8

typedef __attribute__((ext_vector_type(4))) float evf4;
typedef __attribute__((ext_vector_type(8))) short bf16x8;
typedef __attribute__((ext_vector_type(4))) float f32x4;

__device__ __forceinline__ unsigned short bf16rne(float x) {
  unsigned b = __float_as_uint(x);
  unsigned r = b + 0x7FFFu + ((b >> 16) & 1u);
  return (unsigned short)(r >> 16);
}
__device__ __forceinline__ float bf16tof(unsigned short h) {
  return __uint_as_float(((unsigned)h) << 16);
}

// ---- parallel padded-count scan, 3 phases ----
// A: per-256-node block sums of padded counts
__global__ __launch_bounds__(256) void k_scanA(const int* __restrict__ cnt,
                                               int* __restrict__ bsum, int N) {
  int i = blockIdx.x * 256 + threadIdx.x;
  int v = (i < N) ? ((cnt[i] + 15) & ~15) : 0;
#pragma unroll
  for (int o = 32; o > 0; o >>= 1) v += __shfl_xor(v, o, 64);
  __shared__ int ws[4];
  if ((threadIdx.x & 63) == 0) ws[threadIdx.x >> 6] = v;
  __syncthreads();
  if (threadIdx.x == 0) bsum[blockIdx.x] = ws[0] + ws[1] + ws[2] + ws[3];
}

// B: exclusive scan of block sums (nb <= 1024), writes total to rptrN
__global__ __launch_bounds__(1024) void k_scanB(const int* __restrict__ bsum,
                                                int* __restrict__ boff,
                                                int* __restrict__ rptrN, int nb) {
  const int t = threadIdx.x;
  const int lane = t & 63, wid = t >> 6;
  int v = (t < nb) ? bsum[t] : 0;
  int s = v;
#pragma unroll
  for (int o = 1; o < 64; o <<= 1) {
    int u = __shfl_up(s, o, 64);
    if (lane >= o) s += u;
  }
  __shared__ int ws[16];
  if (lane == 63) ws[wid] = s;
  __syncthreads();
  if (wid == 0 && lane < 16) {
    int w = ws[lane];
#pragma unroll
    for (int o = 1; o < 16; o <<= 1) {
      int u = __shfl_up(w, o, 16);
      if (lane >= o) w += u;
    }
    ws[lane] = w;
  }
  __syncthreads();
  int add = wid ? ws[wid - 1] : 0;
  if (t < nb) boff[t] = add + s - v;
  if (t == nb - 1) *rptrN = add + s;
}

// C: per-node rptr2 + dinv + sentinel fill (absorbs old k_prep)
__global__ __launch_bounds__(256) void k_scanC(const int* __restrict__ cnt,
                                               const int* __restrict__ boff,
                                               int* __restrict__ rptr2,
                                               float* __restrict__ dinv,
                                               unsigned short* __restrict__ srcs, int N) {
  const int t = threadIdx.x;
  const int i = blockIdx.x * 256 + t;
  const int lane = t & 63, wid = t >> 6;
  const int cv = (i < N) ? cnt[i] : 0;
  const int v = (i < N) ? ((cv + 15) & ~15) : 0;
  int s = v;
#pragma unroll
  for (int o = 1; o < 64; o <<= 1) {
    int u = __shfl_up(s, o, 64);
    if (lane >= o) s += u;
  }
  __shared__ int ws[4];
  if (lane == 63) ws[wid] = s;
  __syncthreads();
  int add = 0;
  if (wid > 0) add += ws[0];
  if (wid > 1) add += ws[1];
  if (wid > 2) add += ws[2];
  if (i < N) {
    const int base = boff[blockIdx.x] + add + s - v;  // exclusive prefix
    rptr2[i] = base;
    dinv[i] = rsqrtf((float)(cv + 1));
    for (int e = base + cv; e < base + v; ++e) srcs[e] = (unsigned short)N;
  }
}

// phase A: per-node degree count + bin edges into 8 col-range buckets
__global__ __launch_bounds__(256) void k_bin(const int* __restrict__ row,
                                             const int* __restrict__ col,
                                             int* __restrict__ cnt,
                                             int* __restrict__ bfill,
                                             unsigned* __restrict__ pairs,
                                             int E, float bscale, int bshift) {
  __shared__ int lh[NBKT], gbase[NBKT], lcur[NBKT];
  const int tid = threadIdx.x;
  const int chunk = (E + gridDim.x - 1) / gridDim.x;
  const int s0 = blockIdx.x * chunk;
  const int s1 = min(s0 + chunk, E);
  if (tid < NBKT) lh[tid] = 0;
  __syncthreads();
  for (int e = s0 + tid; e < s1; e += 256) {
    int c = col[e];
    atomicAdd(&cnt[c], 1);
    int b = min(NBKT - 1, (int)((float)c * bscale));
    atomicAdd(&lh[b], 1);
  }
  __syncthreads();
  if (tid < NBKT) {
    gbase[tid] = atomicAdd(&bfill[tid], lh[tid]);
    lcur[tid] = 0;
  }
  __syncthreads();
  for (int e = s0 + tid; e < s1; e += 256) {
    int c = col[e], r = row[e];
    int b = min(NBKT - 1, (int)((float)c * bscale));
    int off = atomicAdd(&lcur[b], 1);
    pairs[(b << bshift) + gbase[b] + off] = ((unsigned)r << 16) | (unsigned)c;
  }
}

// phase B: XCD-affine scatter into padded CSR (bucket b on blocks with blockIdx&7==b)
__global__ __launch_bounds__(256) void k_fill2(const unsigned* __restrict__ pairs,
                                               const int* __restrict__ bfill,
                                               const int* __restrict__ rptr2,
                                               int* __restrict__ fillc,
                                               unsigned short* __restrict__ srcs,
                                               int bshift) {
  const int b = blockIdx.x & 7;
  const int bi = blockIdx.x >> 3;
  const int cap = bfill[b];
  const int stride = (gridDim.x >> 3) * blockDim.x;
  const unsigned* __restrict__ bp = pairs + ((size_t)b << bshift);
  for (int idx = bi * blockDim.x + threadIdx.x; idx < cap; idx += stride) {
    unsigned p = bp[idx];
    int c = (int)(p & 0xFFFFu);
    int pos = rptr2[c] + atomicAdd(&fillc[c], 1);
    srcs[pos] = (unsigned short)(p >> 16);
  }
}

// zero the 8 sentinel rows of each of the 3 slice tables
__global__ void k_zsent(float* __restrict__ Tall, int N) {
  int t = blockIdx.x * blockDim.x + threadIdx.x;
  if (t < CLS * 8 * 16) {
    int c = t / 128, rem = t % 128;
    int s = rem / 16, f = rem % 16;
    Tall[((size_t)c * 8 + s) * (size_t)(N + 1) * 16 + (size_t)N * 16 + f] = 0.f;
  }
}

// split conv_w into bf16 hi/lo, TRANSPOSED: WhT[cl][col][k]
__global__ void k_wsplit(const float* __restrict__ W, unsigned short* __restrict__ WhT,
                         unsigned short* __restrict__ WlT, int total) {
  int idx = blockIdx.x * blockDim.x + threadIdx.x;
  if (idx >= total) return;
  int cl = idx >> 14;
  int rem = idx & 16383;
  int c = rem >> 7, k = rem & 127;
  float w = W[(size_t)cl * 16384 + k * 128 + c];
  unsigned short h = bf16rne(w);
  WhT[idx] = h;
  WlT[idx] = bf16rne(w - bf16tof(h));
}

// ---- T0 = x * dinv, slice-major [8][N+1][16] ----
__global__ __launch_bounds__(256) void k_scale(const float* __restrict__ x,
                                               const float* __restrict__ dinv,
                                               float* __restrict__ T, int N) {
  const int s = blockIdx.y;
  const int i = blockIdx.x * 64 + (threadIdx.x >> 2);
  const int f = threadIdx.x & 3;
  if (i < N) {
    float4 v = *(const float4*)&x[(size_t)i * 128 + s * 16 + f * 4];
    float d = dinv[i];
    v.x *= d; v.y *= d; v.z *= d; v.w *= d;
    *(float4*)&T[((size_t)s * (N + 1) + i) * 16 + f * 4] = v;
  }
}

// ---- XCD-sliced gather, fused over classes (blockIdx.y = class); fp32 full-line out ----
__global__ __launch_bounds__(256, 4) void k_gather(const float* __restrict__ Tbase, long tstride,
                                                   const int* __restrict__ rptr2,
                                                   const unsigned short* __restrict__ srcs,
                                                   const float* __restrict__ dinv,
                                                   float* __restrict__ Zbase, long zstride,
                                                   int N) {
  const int s = blockIdx.x & 7;
  const int chunk = blockIdx.x >> 3;
  const int i = chunk * 64 + (threadIdx.x >> 2);
  const int f = threadIdx.x & 3;
  if (i >= N) return;
  const float* __restrict__ T = Tbase + (size_t)blockIdx.y * tstride;
  float* __restrict__ Z = Zbase + (size_t)blockIdx.y * zstride;
  const evf4* __restrict__ Ts = (const evf4*)(T + (size_t)s * (N + 1) * 16);
  const int e0 = rptr2[i], e1 = rptr2[i + 1];
  evf4 a0 = Ts[(size_t)i * 4 + f];  // self term
  evf4 a1 = (evf4)0.f, a2 = (evf4)0.f, a3 = (evf4)0.f;
  uint4 I0 = make_uint4(0, 0, 0, 0), I1 = I0;
  if (e0 < e1) {
    I0 = *(const uint4*)(srcs + e0);
    I1 = *(const uint4*)(srcs + e0 + 8);
  }
  for (int eb = e0; eb < e1; eb += 16) {
    uint4 I0n = I0, I1n = I1;
    if (eb + 16 < e1) {
      I0n = *(const uint4*)(srcs + eb + 16);
      I1n = *(const uint4*)(srcs + eb + 24);
    }
    const int j0  = (int)(I0.x & 0xFFFFu), j1  = (int)(I0.x >> 16);
    const int j2  = (int)(I0.y & 0xFFFFu), j3  = (int)(I0.y >> 16);
    const int j4  = (int)(I0.z & 0xFFFFu), j5  = (int)(I0.z >> 16);
    const int j6  = (int)(I0.w & 0xFFFFu), j7  = (int)(I0.w >> 16);
    const int j8  = (int)(I1.x & 0xFFFFu), j9  = (int)(I1.x >> 16);
    const int j10 = (int)(I1.y & 0xFFFFu), j11 = (int)(I1.y >> 16);
    const int j12 = (int)(I1.z & 0xFFFFu), j13 = (int)(I1.z >> 16);
    const int j14 = (int)(I1.w & 0xFFFFu), j15 = (int)(I1.w >> 16);
    evf4 v0  = Ts[(size_t)j0  * 4 + f];
    evf4 v1  = Ts[(size_t)j1  * 4 + f];
    evf4 v2  = Ts[(size_t)j2  * 4 + f];
    evf4 v3  = Ts[(size_t)j3  * 4 + f];
    evf4 v4  = Ts[(size_t)j4  * 4 + f];
    evf4 v5  = Ts[(size_t)j5  * 4 + f];
    evf4 v6  = Ts[(size_t)j6  * 4 + f];
    evf4 v7  = Ts[(size_t)j7  * 4 + f];
    evf4 v8  = Ts[(size_t)j8  * 4 + f];
    evf4 v9  = Ts[(size_t)j9  * 4 + f];
    evf4 v10 = Ts[(size_t)j10 * 4 + f];
    evf4 v11 = Ts[(size_t)j11 * 4 + f];
    evf4 v12 = Ts[(size_t)j12 * 4 + f];
    evf4 v13 = Ts[(size_t)j13 * 4 + f];
    evf4 v14 = Ts[(size_t)j14 * 4 + f];
    evf4 v15 = Ts[(size_t)j15 * 4 + f];
    asm volatile("" :: "v"(v0), "v"(v1), "v"(v2), "v"(v3),
                       "v"(v4), "v"(v5), "v"(v6), "v"(v7),
                       "v"(v8), "v"(v9), "v"(v10), "v"(v11),
                       "v"(v12), "v"(v13), "v"(v14), "v"(v15));
    __builtin_amdgcn_sched_barrier(0);
    a0 += v0;  a1 += v1;  a2 += v2;  a3 += v3;
    a0 += v4;  a1 += v5;  a2 += v6;  a3 += v7;
    a0 += v8;  a1 += v9;  a2 += v10; a3 += v11;
    a0 += v12; a1 += v13; a2 += v14; a3 += v15;
    I0 = I0n; I1 = I1n;
  }
  const float d = dinv[i];
  evf4 r = (a0 + a1 + a2 + a3) * d;
  *(evf4*)&Z[(size_t)i * 128 + s * 16 + f * 4] = r;
}

// ---- split-bf16 MFMA GEMM (emulated fp32), A split in-kernel from fp32 ----
// C = Ah@Wh + Ah@Wl + Al@Wh (Al@Wl dropped: ~2^-18 rel). 128x128 tile, 4 waves,
// K-step 32. MODE 0: slice-major fp32 table (+dinv); MODE 1: row-major fp32 H.
template <int MODE>
__global__ __launch_bounds__(256) void k_gemm3m(
    const float* __restrict__ Abase, long astride,
    const unsigned short* __restrict__ WhT, const unsigned short* __restrict__ WlT,
    int layer, const float* __restrict__ bl, const float* __restrict__ dinv,
    float* __restrict__ Obase, long ostride, int N) {
  __shared__ unsigned short Ash[128 * 40], Asl[128 * 40];
  __shared__ unsigned short Wsh[128 * 40], Wsl[128 * 40];
  __shared__ float red[128][2];

  const int c = blockIdx.y;
  const float* __restrict__ A = Abase + (size_t)c * astride;
  const size_t wslab = (size_t)(c * LAY + layer) * 16384;
  const float* __restrict__ bias = bl + (size_t)(c * LAY + layer) * D;
  float* __restrict__ Out = Obase + (size_t)c * ostride;

  const int tid = threadIdx.x;
  const int w = tid >> 6, l = tid & 63;
  const int wr = w >> 1, wc = w & 1;
  const int lg = l >> 4, li = l & 15;
  const int m0 = blockIdx.x * 128;

  f32x4 acc[4][4];
#pragma unroll
  for (int i = 0; i < 4; ++i)
#pragma unroll
    for (int j = 0; j < 4; ++j) acc[i][j] = (f32x4)0.f;

  const int srow = tid >> 1;
  const int half = tid & 1;
  const bool rowok = (m0 + srow) < N;

  for (int kc = 0; kc < 128; kc += 32) {
    float fa[16];
#pragma unroll
    for (int j = 0; j < 16; ++j) fa[j] = 0.f;
    if (rowok) {
      const size_t ab = (size_t)(m0 + srow) * 128 + kc + half * 16;
      *(float4*)&fa[0]  = *(const float4*)&A[ab];
      *(float4*)&fa[4]  = *(const float4*)&A[ab + 4];
      *(float4*)&fa[8]  = *(const float4*)&A[ab + 8];
      *(float4*)&fa[12] = *(const float4*)&A[ab + 12];
    }
    const size_t wb = wslab + (size_t)srow * 128 + kc + half * 16;
    uint4 wh0 = *(const uint4*)&WhT[wb];
    uint4 wh1 = *(const uint4*)&WhT[wb + 8];
    uint4 wl0 = *(const uint4*)&WlT[wb];
    uint4 wl1 = *(const uint4*)&WlT[wb + 8];

    unsigned hpk[8], lpk[8];
#pragma unroll
    for (int j = 0; j < 8; ++j) {
      unsigned short h0 = bf16rne(fa[2 * j]);
      unsigned short h1 = bf16rne(fa[2 * j + 1]);
      float l0 = fa[2 * j] - bf16tof(h0);
      float l1 = fa[2 * j + 1] - bf16tof(h1);
      hpk[j] = (unsigned)h0 | ((unsigned)h1 << 16);
      lpk[j] = (unsigned)bf16rne(l0) | ((unsigned)bf16rne(l1) << 16);
    }
    if (kc) __syncthreads();
    *(uint4*)&Ash[srow * 40 + half * 16]     = make_uint4(hpk[0], hpk[1], hpk[2], hpk[3]);
    *(uint4*)&Ash[srow * 40 + half * 16 + 8] = make_uint4(hpk[4], hpk[5], hpk[6], hpk[7]);
    *(uint4*)&Asl[srow * 40 + half * 16]     = make_uint4(lpk[0], lpk[1], lpk[2], lpk[3]);
    *(uint4*)&Asl[srow * 40 + half * 16 + 8] = make_uint4(lpk[4], lpk[5], lpk[6], lpk[7]);
    *(uint4*)&Wsh[srow * 40 + half * 16]     = wh0;
    *(uint4*)&Wsh[srow * 40 + half * 16 + 8] = wh1;
    *(uint4*)&Wsl[srow * 40 + half * 16]     = wl0;
    *(uint4*)&Wsl[srow * 40 + half * 16 + 8] = wl1;
    __syncthreads();

    bf16x8 fah[4], fal[4];
#pragma unroll
    for (int rf = 0; rf < 4; ++rf) {
      const int arow = wr * 64 + rf * 16 + li;
      fah[rf] = *(const bf16x8*)&Ash[arow * 40 + lg * 8];
      fal[rf] = *(const bf16x8*)&Asl[arow * 40 + lg * 8];
    }
#pragma unroll
    for (int cf = 0; cf < 4; ++cf) {
      const int bcol = wc * 64 + cf * 16 + li;
      bf16x8 fbh = *(const bf16x8*)&Wsh[bcol * 40 + lg * 8];
      bf16x8 fbl = *(const bf16x8*)&Wsl[bcol * 40 + lg * 8];
#pragma unroll
      for (int rf = 0; rf < 4; ++rf) {
        acc[rf][cf] = __builtin_amdgcn_mfma_f32_16x16x32_bf16(fah[rf], fbh, acc[rf][cf], 0, 0, 0);
        acc[rf][cf] = __builtin_amdgcn_mfma_f32_16x16x32_bf16(fah[rf], fbl, acc[rf][cf], 0, 0, 0);
        acc[rf][cf] = __builtin_amdgcn_mfma_f32_16x16x32_bf16(fal[rf], fbh, acc[rf][cf], 0, 0, 0);
      }
    }
  }
  __syncthreads();

  // epilogue: bias, row L2-norm (cross-lane + cross-wave), relu, (dinv), store
  float bj[4];
#pragma unroll
  for (int cf = 0; cf < 4; ++cf) bj[cf] = bias[wc * 64 + cf * 16 + li];
#pragma unroll
  for (int rf = 0; rf < 4; ++rf) {
#pragma unroll
    for (int r = 0; r < 4; ++r) {
      float sq = 0.f;
#pragma unroll
      for (int cf = 0; cf < 4; ++cf) {
        float v = acc[rf][cf][r] + bj[cf];
        acc[rf][cf][r] = v;
        sq = fmaf(v, v, sq);
      }
#pragma unroll
      for (int m = 1; m < 16; m <<= 1) sq += __shfl_xor(sq, m, 16);
      if (li == 0) red[wr * 64 + rf * 16 + lg * 4 + r][wc] = sq;
    }
  }
  __syncthreads();
#pragma unroll
  for (int rf = 0; rf < 4; ++rf) {
#pragma unroll
    for (int r = 0; r < 4; ++r) {
      const int rrow = wr * 64 + rf * 16 + lg * 4 + r;
      const int grow = m0 + rrow;
      if (grow >= N) continue;
      float rsum = red[rrow][0] + red[rrow][1];
      float sc = 1.0f / fmaxf(sqrtf(rsum), 1e-12f);
      if (MODE == 0) sc *= dinv[grow];
#pragma unroll
      for (int cf = 0; cf < 4; ++cf) {
        float v = fmaxf(acc[rf][cf][r] * sc, 0.f);
        if (MODE == 0) {
          const int sidx = wc * 4 + cf;
          Out[((size_t)sidx * (N + 1) + grow) * 16 + li] = v;
        } else {
          Out[(size_t)grow * 128 + wc * 64 + cf * 16 + li] = v;
        }
      }
    }
  }
}

// ------------- batched head: pool + lin1 + ReLU + lin2 (blockIdx.y = class) -------------
__device__ __forceinline__ int lowerb(const int* __restrict__ a, int n, int v) {
  int lo = 0, hi = n;
  while (lo < hi) {
    int m = (lo + hi) >> 1;
    if (a[m] < v) lo = m + 1; else hi = m;
  }
  return lo;
}

__global__ __launch_bounds__(128) void k_head(const float* __restrict__ Hall, long hstride,
                                              const int* __restrict__ batch, int N,
                                              const float* __restrict__ l1w,
                                              const float* __restrict__ l1b,
                                              const float* __restrict__ l2w,
                                              const float* __restrict__ l2b,
                                              float* __restrict__ out, int G) {
  const int g = blockIdx.x;
  const int c = blockIdx.y;
  const int t = threadIdx.x;
  const float* __restrict__ h = Hall + (size_t)c * hstride;
  const float* __restrict__ w1 = l1w + (size_t)c * D * D;
  const float* __restrict__ w2 = l2w + (size_t)c * D;
  int lo = lowerb(batch, N, g);
  int hi = lowerb(batch, N, g + 1);
  float p = 0.f;
  for (int i = lo; i < hi; ++i) p += h[(size_t)i * 128 + t];
  __shared__ float pl[128];
  pl[t] = p;
  __syncthreads();
  float z = l1b[(size_t)c * D + t];
#pragma unroll 8
  for (int k = 0; k < 128; ++k) z = fmaf(pl[k], w1[k * 128 + t], z);
  z = fmaxf(z, 0.f);
  float o = z * w2[t];
#pragma unroll
  for (int off = 32; off > 0; off >>= 1) o += __shfl_xor(o, off, 64);
  __shared__ float s2[2];
  if ((t & 63) == 0) s2[t >> 6] = o;
  __syncthreads();
  if (t == 0) out[(size_t)g * CLS + c] = s2[0] + s2[1] + l2b[c];
}

extern "C" void kernel_launch(void* const* d_in, const int* in_sizes, int n_in,
                              void* d_out, int out_size, void* d_ws, size_t ws_size,
                              hipStream_t stream) {
  const float* x = (const float*)d_in[0];
  const int* eidx = (const int*)d_in[1];
  const int* batch = (const int*)d_in[2];
  const float* conv_w = (const float*)d_in[3];
  const float* conv_b = (const float*)d_in[4];
  const float* lin1_w = (const float*)d_in[5];
  const float* lin1_b = (const float*)d_in[6];
  const float* lin2_w = (const float*)d_in[7];
  const float* lin2_b = (const float*)d_in[8];
  float* out = (float*)d_out;

  const int N = in_sizes[0] / D;
  const int E = in_sizes[1] / 2;
  const int G = out_size / CLS;
  const int* row = eidx;
  const int* col = eidx + E;

  int bshift = 10;
  while ((1 << bshift) < E / NBKT + 32768) ++bshift;
  const long TS = (long)(N + 1) * 128;  // per-class slice-table stride (floats)
  const long ZS = (long)N * 128;        // per-class row-major stride (floats)

  char* ws = (char*)d_ws;
  size_t off = 0;
  auto alloc = [&](size_t bytes) -> void* {
    void* p = ws + off;
    off += (bytes + 255) & ~(size_t)255;
    return p;
  };
  float* Zall = (float*)alloc((size_t)CLS * ZS * 4);
  float* Tall = (float*)alloc((size_t)CLS * TS * 4);
  unsigned short* WhT = (unsigned short*)alloc((size_t)CLS * LAY * D * D * 2);
  unsigned short* WlT = (unsigned short*)alloc((size_t)CLS * LAY * D * D * 2);
  unsigned short* srcs = (unsigned short*)alloc(((size_t)E + 16 * (size_t)N + 64) * 2);
  int* cnt    = (int*)alloc(((size_t)N * 2 + NBKT) * 4);
  int* fillc  = cnt + N;
  int* bfill  = cnt + 2 * N;
  int* rptr2  = (int*)alloc((size_t)(N + 1) * 4);
  float* dinv = (float*)alloc((size_t)N * 4);
  int* bsum   = (int*)alloc(1024 * 4 * 2);  // scan partials + offsets
  int* boff   = bsum + 1024;
  unsigned* pairs = (unsigned*)Tall;  // alias: dead before k_zsent/k_scale
  (void)ws_size; (void)n_in;

  hipMemsetAsync(cnt, 0, ((size_t)N * 2 + NBKT) * 4, stream);
  const int wtot = CLS * LAY * D * D;
  const int sb = (N + 255) / 256;
  k_bin<<<1024, 256, 0, stream>>>(row, col, cnt, bfill, pairs, E, (float)NBKT / (float)N, bshift);
  k_scanA<<<sb, 256, 0, stream>>>(cnt, bsum, N);
  k_scanB<<<1, 1024, 0, stream>>>(bsum, boff, rptr2 + N, sb);
  k_scanC<<<sb, 256, 0, stream>>>(cnt, boff, rptr2, dinv, srcs, N);
  k_fill2<<<1024, 256, 0, stream>>>(pairs, bfill, rptr2, fillc, srcs, bshift);
  k_zsent<<<2, 256, 0, stream>>>(Tall, N);
  k_wsplit<<<(wtot + 255) / 256, 256, 0, stream>>>(conv_w, WhT, WlT, wtot);

  const int NB64 = (N + 63) / 64;
  const int gb = (N + 127) / 128;
  float* Z0 = Zall;

  // shared layer 0
  k_scale<<<dim3(NB64, 8), 256, 0, stream>>>(x, dinv, Tall, N);
  k_gather<<<dim3(NB64 * 8, 1), 256, 0, stream>>>(Tall, 0L, rptr2, srcs, dinv, Z0, 0L, N);

  // layer 1 (A shared across classes)
  k_gemm3m<0><<<dim3(gb, CLS), 256, 0, stream>>>(Z0, 0L, WhT, WlT, 0,
                                                 conv_b, dinv, Tall, TS, N);
  k_gather<<<dim3(NB64 * 8, CLS), 256, 0, stream>>>(Tall, TS, rptr2, srcs, dinv, Zall, ZS, N);

  // layer 2
  k_gemm3m<0><<<dim3(gb, CLS), 256, 0, stream>>>(Zall, ZS, WhT, WlT, 1,
                                                 conv_b, dinv, Tall, TS, N);
  k_gather<<<dim3(NB64 * 8, CLS), 256, 0, stream>>>(Tall, TS, rptr2, srcs, dinv, Zall, ZS, N);

  // layer 3 -> H (row-major fp32, stored in the table slots)
  k_gemm3m<1><<<dim3(gb, CLS), 256, 0, stream>>>(Zall, ZS, WhT, WlT, 2,
                                                 conv_b, dinv, Tall, TS, N);

  // heads
  k_head<<<dim3(G, CLS), 128, 0, stream>>>(Tall, TS, batch, N,
                                           lin1_w, lin1_b, lin2_w, lin2_b, out, G);
}